// Round 12
// baseline (217.019 us; speedup 1.0000x reference)
//
#include <hip/hip_runtime.h>
#include <cstdint>
#include <cstddef>
#include <cmath>

#define EPS_COS 1e-8f

typedef unsigned short u16;
typedef __attribute__((ext_vector_type(8))) short short8v;
typedef __attribute__((ext_vector_type(4))) short short4v;
typedef __attribute__((ext_vector_type(4))) float f32x4;

__device__ __forceinline__ u16 f2bf(float x) {
    unsigned int u = __float_as_uint(x);
    return (u16)((u + 0x7FFFu + ((u >> 16) & 1u)) >> 16);  // RNE
}
__device__ __forceinline__ float bf2f(u16 h) {
    return __uint_as_float(((unsigned int)h) << 16);
}

// ---------------------------------------------------------------------------
// fused row L2 norm + bf16 convert (C fixed = 1024), one block per row
// ---------------------------------------------------------------------------
__global__ __launch_bounds__(256) void norm_cvt_kernel(const float* __restrict__ src,
                                                       u16* __restrict__ dst, int dstStride,
                                                       float* __restrict__ norms) {
    int r = blockIdx.x;
    int t = threadIdx.x;
    const float4 v = *reinterpret_cast<const float4*>(&src[(size_t)r * 1024 + t * 4]);
    short4v o;
    o[0] = f2bf(v.x); o[1] = f2bf(v.y); o[2] = f2bf(v.z); o[3] = f2bf(v.w);
    *reinterpret_cast<short4v*>(&dst[(size_t)r * dstStride + t * 4]) = o;
    float ss = v.x * v.x + v.y * v.y + v.z * v.z + v.w * v.w;
#pragma unroll
    for (int off = 32; off > 0; off >>= 1) ss += __shfl_down(ss, off);
    __shared__ float red[4];
    int wave = t >> 6, lane = t & 63;
    if (lane == 0) red[wave] = ss;
    __syncthreads();
    if (t == 0) norms[r] = sqrtf(red[0] + red[1] + red[2] + red[3]);
}

// ---------------------------------------------------------------------------
// transpose + cvt: src [R][C] f32 -> dst [C][R] bf16 (64x64 LDS tiles, +1 pad)
// ---------------------------------------------------------------------------
__global__ __launch_bounds__(256) void transpose_cvt_kernel(const float* __restrict__ src,
                                                            u16* __restrict__ dst,
                                                            int R, int C) {
    __shared__ float tile[64][65];
    int c0 = blockIdx.x * 64, r0 = blockIdx.y * 64;
    int t = threadIdx.x;
#pragma unroll
    for (int j = 0; j < 16; ++j) {
        int idx = j * 256 + t;
        int r = idx >> 6, c = idx & 63;
        tile[r][c] = src[(size_t)(r0 + r) * C + c0 + c];
    }
    __syncthreads();
#pragma unroll
    for (int j = 0; j < 16; ++j) {
        int idx = j * 256 + t;
        int c = idx >> 6, r = idx & 63;
        dst[(size_t)(c0 + c) * R + r0 + r] = f2bf(tile[r][c]);
    }
}

// ---------------------------------------------------------------------------
// merged prep: [0,165888) zero hp; [..+131072) ct1_w -> wt1bf;
// [..+16384) ct2_w -> wpad; [..+8192) zero pooled. 1256 blocks x 256.
// ---------------------------------------------------------------------------
__global__ __launch_bounds__(256) void prep_kernel(u16* __restrict__ hp,
                                                   const float* __restrict__ ct1w,
                                                   u16* __restrict__ wt,
                                                   const float* __restrict__ ct2w,
                                                   u16* __restrict__ wpad,
                                                   float* __restrict__ pooled) {
    int idx = blockIdx.x * 256 + threadIdx.x;
    if (idx < 165888) {
        short8v zv = {0, 0, 0, 0, 0, 0, 0, 0};
        *reinterpret_cast<short8v*>(hp + (size_t)idx * 8) = zv;
    } else if (idx < 165888 + 131072) {
        int i = idx - 165888;  // ic*256+oc
        int oc = i & 255, ic = i >> 8;
        float v[16];
#pragma unroll
        for (int j = 0; j < 16; ++j) v[j] = ct1w[(size_t)i * 16 + j];
#pragma unroll
        for (int pp = 0; pp < 4; ++pp) {
            int py = pp >> 1, px = pp & 1;
#pragma unroll
            for (int tap = 0; tap < 4; ++tap) {
                int ty = tap >> 1, tx = tap & 1;
                int ky = (1 - py) + 2 * ty;
                int kx = (1 - px) + 2 * tx;
                wt[((size_t)(pp * 256 + oc)) * 2048 + ic * 4 + tap] = f2bf(v[ky * 4 + kx]);
            }
        }
    } else if (idx < 165888 + 131072 + 16384) {
        int i = idx - 165888 - 131072;
        int ic = i & 255;
        int col = i >> 8;
        float v = 0.0f;
        if (col < 48) {
            int kx = col & 3, ky = (col >> 2) & 3, oc = col >> 4;
            v = ct2w[((size_t)ic * 3 + oc) * 16 + ky * 4 + kx];
        }
        wpad[i] = f2bf(v);
    } else {
        int i = idx - 165888 - 131072 - 16384;  // < 8192
        *reinterpret_cast<f32x4*>(pooled + (size_t)i * 4) = (f32x4){0.f, 0.f, 0.f, 0.f};
    }
}

// ---------------------------------------------------------------------------
// bf16 MFMA GEMM, all-NT, BK=64 reg-staged: C = A[M,K] * B[N,K]^T
// blockIdx.z selects (A,B) via zsA/zsB. BM=FM*32, BN=FN*32; 4 waves (2x2).
// LDS: [row][64 k] bf16; 16B chunk c stored at slot c^(row&7) (8-way XOR ->
// ds_read 2-way aliasing = free). SWZ: XCD-aware flat remap (nwg%8==0 only).
// EPI 0: fp32 store Cf[M][N]
// EPI 1: bf16 store Cb[row*sCb+col]
// EPI 2: g=sigmoid(acc+bias[col]); fused = g*z + (1-g)*z_hat (BOTH bf16 from
//        zbf/zhbf, stride szh); atomicAdd per-(batch,col) into outf (pooled)
// EPI 3: relu(acc+bias[col]) -> bf16 Cb[((b*4+z)*49+s)*256+col], row<1568
// ---------------------------------------------------------------------------
template <int FM, int FN, int EPI, bool SWZ>
__global__ __launch_bounds__(256) void mfma_gemm_kernel(
    const u16* __restrict__ A, int sA, size_t zsA,
    const u16* __restrict__ B, int sB, size_t zsB,
    int M, int N, int K,
    float* __restrict__ Cf,
    u16* __restrict__ Cb, int sCb,
    const float* __restrict__ bias,
    const u16* __restrict__ zbf,
    const u16* __restrict__ zhbf, int szh,
    float* __restrict__ outf) {
    constexpr int BM = FM * 32, BN = FN * 32;
    constexpr int NA = BM / 32;  // short8 chunks per thread (A), BK=64
    constexpr int NB = BN / 32;
    __shared__ __align__(16) u16 As[BM * 64];
    __shared__ __align__(16) u16 Bs[BN * 64];
    int bx = blockIdx.x, by = blockIdx.y;
    if (SWZ) {
        int gx = gridDim.x;
        int nwg = gx * gridDim.y;
        int lb = by * gx + bx;
        int flat = (lb & 7) * (nwg >> 3) + (lb >> 3);
        bx = flat % gx;
        by = flat / gx;
    }
    A += (size_t)blockIdx.z * zsA;
    B += (size_t)blockIdx.z * zsB;
    const int t = threadIdx.x;
    const int lane = t & 63;
    const int wid = t >> 6;
    const int wm = wid >> 1, wn = wid & 1;
    const int m0 = bx * BM, n0 = by * BN;
    const int g = lane >> 4, lr = lane & 15;

    f32x4 acc[FM][FN];
#pragma unroll
    for (int i = 0; i < FM; ++i)
#pragma unroll
        for (int j = 0; j < FN; ++j) acc[i][j] = (f32x4){0.f, 0.f, 0.f, 0.f};

    short8v ra[NA], rb[NB];
#pragma unroll
    for (int j = 0; j < NA; ++j) {
        int c = j * 256 + t, row = c >> 3, ck = c & 7;
        ra[j] = *reinterpret_cast<const short8v*>(A + (size_t)(m0 + row) * sA + ck * 8);
    }
#pragma unroll
    for (int j = 0; j < NB; ++j) {
        int c = j * 256 + t, row = c >> 3, ck = c & 7;
        rb[j] = *reinterpret_cast<const short8v*>(B + (size_t)(n0 + row) * sB + ck * 8);
    }

    for (int k0 = 0; k0 < K; k0 += 64) {
        __syncthreads();
#pragma unroll
        for (int j = 0; j < NA; ++j) {
            int c = j * 256 + t, row = c >> 3, ck = c & 7;
            *reinterpret_cast<short8v*>(As + row * 64 + ((ck ^ (row & 7)) << 3)) = ra[j];
        }
#pragma unroll
        for (int j = 0; j < NB; ++j) {
            int c = j * 256 + t, row = c >> 3, ck = c & 7;
            *reinterpret_cast<short8v*>(Bs + row * 64 + ((ck ^ (row & 7)) << 3)) = rb[j];
        }
        __syncthreads();
        if (k0 + 64 < K) {  // prefetch next tile into regs, overlaps MFMA below
#pragma unroll
            for (int j = 0; j < NA; ++j) {
                int c = j * 256 + t, row = c >> 3, ck = c & 7;
                ra[j] = *reinterpret_cast<const short8v*>(A + (size_t)(m0 + row) * sA + k0 + 64 + ck * 8);
            }
#pragma unroll
            for (int j = 0; j < NB; ++j) {
                int c = j * 256 + t, row = c >> 3, ck = c & 7;
                rb[j] = *reinterpret_cast<const short8v*>(B + (size_t)(n0 + row) * sB + k0 + 64 + ck * 8);
            }
        }
#pragma unroll
        for (int kk = 0; kk < 2; ++kk) {
            short8v af[FM], bfr[FN];
#pragma unroll
            for (int fm = 0; fm < FM; ++fm) {
                int row = wm * (FM * 16) + fm * 16 + lr;
                int rc = (kk * 4 + g) ^ (row & 7);
                af[fm] = *reinterpret_cast<const short8v*>(As + row * 64 + rc * 8);
            }
#pragma unroll
            for (int fn = 0; fn < FN; ++fn) {
                int col = wn * (FN * 16) + fn * 16 + lr;
                int rc = (kk * 4 + g) ^ (col & 7);
                bfr[fn] = *reinterpret_cast<const short8v*>(Bs + col * 64 + rc * 8);
            }
#pragma unroll
            for (int fm = 0; fm < FM; ++fm)
#pragma unroll
                for (int fn = 0; fn < FN; ++fn)
                    acc[fm][fn] = __builtin_amdgcn_mfma_f32_16x16x32_bf16(
                        af[fm], bfr[fn], acc[fm][fn], 0, 0, 0);
        }
    }

    if (EPI == 2) {
        // gate + blend (both operands bf16, resident rows of Abig) + pool
#pragma unroll
        for (int fn = 0; fn < FN; ++fn) {
            int col = n0 + wn * (FN * 16) + fn * 16 + lr;
            int base = m0 + wm * (FM * 16) + g * 4;
            int b0 = base / 196;
            float p0 = 0.f, p1 = 0.f;
#pragma unroll
            for (int fm = 0; fm < FM; ++fm) {
#pragma unroll
                for (int r = 0; r < 4; ++r) {
                    int row = base + fm * 16 + r;
                    float v = acc[fm][fn][r];
                    float gs = 1.0f / (1.0f + __expf(-(v + bias[col])));
                    float zv = bf2f(zbf[(size_t)row * szh + col]);
                    float zh = bf2f(zhbf[(size_t)row * szh + col]);
                    float fused = gs * zv + (1.0f - gs) * zh;
                    bool same = (row / 196) == b0;
                    p0 += same ? fused : 0.f;
                    p1 += same ? 0.f : fused;
                }
            }
            atomicAdd(&outf[(size_t)b0 * 1024 + col], p0);
            if (p1 != 0.f) atomicAdd(&outf[(size_t)(b0 + 1) * 1024 + col], p1);
        }
    } else {
#pragma unroll
        for (int fm = 0; fm < FM; ++fm) {
#pragma unroll
            for (int fn = 0; fn < FN; ++fn) {
#pragma unroll
                for (int r = 0; r < 4; ++r) {
                    int row = m0 + wm * (FM * 16) + fm * 16 + g * 4 + r;
                    int col = n0 + wn * (FN * 16) + fn * 16 + lr;
                    float v = acc[fm][fn][r];
                    if (EPI == 0) {
                        Cf[(size_t)row * N + col] = v;
                    } else if (EPI == 1) {
                        Cb[(size_t)row * sCb + col] = f2bf(v);
                    } else {  // EPI == 3
                        if (row < 1568) {
                            float vv = fmaxf(v + bias[col], 0.0f);
                            int bb = row / 49, ss = row - bb * 49;
                            Cb[(((size_t)bb * 4 + blockIdx.z) * 49 + ss) * 256 + col] = f2bf(vv);
                        }
                    }
                }
            }
        }
    }
}

// ---------------------------------------------------------------------------
// softmax over K=512 with cosine scaling; writes attn (fp32, d_out) + bf16 copy
// ---------------------------------------------------------------------------
__global__ __launch_bounds__(256) void softmax_kernel(const float* __restrict__ dots,
                                                      const float* __restrict__ zn,
                                                      const float* __restrict__ pn,
                                                      float* __restrict__ attn,
                                                      u16* __restrict__ attn_bf) {
    int m = blockIdx.x;
    int t = threadIdx.x;
    float zm = zn[m];
    float d0 = dots[(size_t)m * 512 + t];
    float d1 = dots[(size_t)m * 512 + t + 256];
    float v0 = d0 / fmaxf(zm * pn[t], EPS_COS);
    float v1 = d1 / fmaxf(zm * pn[t + 256], EPS_COS);
    float mx = fmaxf(v0, v1);
#pragma unroll
    for (int off = 32; off > 0; off >>= 1) mx = fmaxf(mx, __shfl_down(mx, off));
    __shared__ float red[8];
    int wave = t >> 6, lane = t & 63;
    if (lane == 0) red[wave] = mx;
    __syncthreads();
    if (t == 0) red[4] = fmaxf(fmaxf(red[0], red[1]), fmaxf(red[2], red[3]));
    __syncthreads();
    mx = red[4];
    float e0 = expf(v0 - mx), e1 = expf(v1 - mx);
    float s = e0 + e1;
#pragma unroll
    for (int off = 32; off > 0; off >>= 1) s += __shfl_down(s, off);
    if (lane == 0) red[wave] = s;
    __syncthreads();
    if (t == 0) red[5] = 1.0f / (red[0] + red[1] + red[2] + red[3]);
    __syncthreads();
    float r = red[5];
    float a0 = e0 * r, a1 = e1 * r;
    attn[(size_t)m * 512 + t] = a0;
    attn[(size_t)m * 512 + t + 256] = a1;
    attn_bf[(size_t)m * 512 + t] = f2bf(a0);
    attn_bf[(size_t)m * 512 + t + 256] = f2bf(a1);
}

// ---------------------------------------------------------------------------
// dec split-K phase 1: partial[kc][b][c] = sum_{k in 64-chunk} pooled[b][k]*W[k][c]
// grid (98,16) = 1568 blocks. LOAD-BATCH idiom: 8 f32x4 loads issued into a
// static-indexed array BEFORE any use (outer loop unroll 1 keeps the batch) —
// r8/r11 showed the compiler sinks interleaved load;use to ~1 in flight
// (VGPR 56). Partials stored bf16 (halves write traffic).
// ---------------------------------------------------------------------------
#define DEC_KC 64
__global__ __launch_bounds__(256) void dec_split_kernel(const float* __restrict__ pooled,
                                                        const float* __restrict__ dec_w,
                                                        u16* __restrict__ partial) {
    const int t = threadIdx.x;
    const int lane = t & 63;
    const int wv = t >> 6;  // 0..3
    const int c = blockIdx.x * 256 + lane * 4;
    const int kc = blockIdx.y;
    __shared__ float pl[32][DEC_KC];
    for (int i = t; i < 32 * DEC_KC; i += 256) {
        int b = i >> 6, kk = i & (DEC_KC - 1);
        pl[b][kk] = pooled[(size_t)b * 1024 + kc * DEC_KC + kk] * (1.0f / 196.0f);
    }
    __syncthreads();
    f32x4 acc[8];
#pragma unroll
    for (int j = 0; j < 8; ++j) acc[j] = (f32x4){0.f, 0.f, 0.f, 0.f};
    const float* wp = dec_w + (size_t)(kc * DEC_KC) * 25088 + c;
#pragma unroll 1
    for (int k = 0; k < DEC_KC; k += 8) {
        f32x4 wv8[8];
#pragma unroll
        for (int q = 0; q < 8; ++q)
            wv8[q] = *reinterpret_cast<const f32x4*>(wp + (size_t)(k + q) * 25088);
#pragma unroll
        for (int q = 0; q < 8; ++q) {
#pragma unroll
            for (int j = 0; j < 8; ++j) {
                float pv = pl[wv * 8 + j][k + q];
                acc[j].x = fmaf(pv, wv8[q].x, acc[j].x);
                acc[j].y = fmaf(pv, wv8[q].y, acc[j].y);
                acc[j].z = fmaf(pv, wv8[q].z, acc[j].z);
                acc[j].w = fmaf(pv, wv8[q].w, acc[j].w);
            }
        }
    }
#pragma unroll
    for (int j = 0; j < 8; ++j) {
        int b = wv * 8 + j;
        short4v o;
        o[0] = f2bf(acc[j].x); o[1] = f2bf(acc[j].y);
        o[2] = f2bf(acc[j].z); o[3] = f2bf(acc[j].w);
        *reinterpret_cast<short4v*>(partial + ((size_t)kc * 32 + b) * 25088 + c) = o;
    }
}

// ---------------------------------------------------------------------------
// dec split-K phase 2: h[b][c] = sum_{kc<16} bf16 partial + dec_b[c] -> bf16 hp
// 2 cols/thread (packed u32 reads), grid (49, 32)
// ---------------------------------------------------------------------------
__global__ __launch_bounds__(256) void dec_reduce_kernel(const u16* __restrict__ partial,
                                                         const float* __restrict__ dec_b,
                                                         u16* __restrict__ hp) {
    int c = (blockIdx.x * 256 + threadIdx.x) * 2;
    int b = blockIdx.y;
    float2 bb = *reinterpret_cast<const float2*>(&dec_b[c]);
    float s0 = bb.x, s1 = bb.y;
#pragma unroll
    for (int kc = 0; kc < 16; ++kc) {
        unsigned int v = *reinterpret_cast<const unsigned int*>(
            partial + ((size_t)kc * 32 + b) * 25088 + c);
        s0 += bf2f((u16)(v & 0xffffu));
        s1 += bf2f((u16)(v >> 16));
    }
#pragma unroll
    for (int q = 0; q < 2; ++q) {
        int cc = c + q;
        float s = q ? s1 : s0;
        int ic = cc / 49, sp = cc - ic * 49;
        int sy = sp / 7, sx = sp - sy * 7;
        hp[((size_t)b * 512 + ic) * 81 + (sy + 1) * 9 + sx + 1] = f2bf(s);
    }
}

// ---------------------------------------------------------------------------
// im2col for convT1 parity classes: A[p][row=b*49+s][k=ic*4+tap] bf16
// ---------------------------------------------------------------------------
__global__ __launch_bounds__(256) void im2col_kernel(const u16* __restrict__ hp,
                                                     u16* __restrict__ A) {
    int idx = blockIdx.x * 256 + threadIdx.x;  // < 1,638,400
    int k8 = idx & 255;                        // 8 cols = 2 ic x 4 taps
    int pr = idx >> 8;
    int p = pr / 1600;
    int row = pr - p * 1600;
    short8v o = {0, 0, 0, 0, 0, 0, 0, 0};
    if (row < 1568) {
        int b = row / 49, s = row - b * 49;
        int sy = s / 7, sx = s - sy * 7;
        int r0 = sy + (p >> 1) + 1;
        int c0 = sx + (p & 1) + 1;
        int ic0 = k8 * 2;
        const u16* hb = hp + ((size_t)b * 512 + ic0) * 81;
#pragma unroll
        for (int j = 0; j < 2; ++j) {
            o[j * 4 + 0] = hb[r0 * 9 + c0];
            o[j * 4 + 1] = hb[r0 * 9 + c0 - 1];
            o[j * 4 + 2] = hb[(r0 - 1) * 9 + c0];
            o[j * 4 + 3] = hb[(r0 - 1) * 9 + c0 - 1];
            hb += 81;
        }
    }
    *reinterpret_cast<short8v*>(A + (size_t)idx * 8) = o;
}

// ---------------------------------------------------------------------------
// convT2 gather: out[o] = bias[oc] + sum_{<=4 taps} G[row][oc*16+ky*4+kx]
// ---------------------------------------------------------------------------
__global__ __launch_bounds__(256) void convt2_gather_kernel(const float* __restrict__ G,
                                                            const float* __restrict__ bias,
                                                            float* __restrict__ out) {
    int o = blockIdx.x * 256 + threadIdx.x;  // < 75264
    int ox = o % 28;
    int oy = (o / 28) % 28;
    int oc = (o / 784) % 3;
    int b = o / 2352;
    int by = (oy + 1) >> 1, bx = (ox + 1) >> 1;
    float acc = bias[oc];
#pragma unroll
    for (int ty = 0; ty < 2; ++ty) {
        int iy = by - ty;
        if ((unsigned)iy >= 14u) continue;
#pragma unroll
        for (int tx = 0; tx < 2; ++tx) {
            int ix = bx - tx;
            if ((unsigned)ix >= 14u) continue;
            int p = (iy & 1) * 2 + (ix & 1);
            int row = ((b * 4 + p) * 49) + (iy >> 1) * 7 + (ix >> 1);
            int ky = oy + 1 - 2 * iy, kx = ox + 1 - 2 * ix;
            acc += G[(size_t)row * 64 + oc * 16 + ky * 4 + kx];
        }
    }
    out[o] = acc;
}

// ---------------------------------------------------------------------------
extern "C" void kernel_launch(void* const* d_in, const int* in_sizes, int n_in,
                              void* d_out, int out_size, void* d_ws, size_t ws_size,
                              hipStream_t stream) {
    const float* z      = (const float*)d_in[0];  // [32,196,1024]
    const float* protos = (const float*)d_in[1];  // [512,1024]
    const float* gate_w = (const float*)d_in[2];  // [2048,1024]
    const float* gate_b = (const float*)d_in[3];  // [1024]
    const float* dec_w  = (const float*)d_in[4];  // [1024,25088]
    const float* dec_b  = (const float*)d_in[5];  // [25088]
    const float* ct1_w  = (const float*)d_in[6];  // [512,256,4,4]
    const float* ct1_b  = (const float*)d_in[7];  // [256]
    const float* ct2_w  = (const float*)d_in[8];  // [256,3,4,4]
    const float* ct2_b  = (const float*)d_in[9];  // [3]

    float* xout = (float*)d_out;   // x_recon 75264
    float* attn = xout + 75264;    // attn 3211264

    float* w = (float*)d_ws;
    float* pn        = w;                       // 512
    float* zn        = w + 512;                 // 6272
    float* pooled    = w + 6784;                // 32768 (atomic-accumulated token sums)
    u16*   wt1bf     = (u16*)(w + 51840);       // 2,097,152 u16 -> ends 1,100,416
    u16*   protos_bf = (u16*)(w + 1100416);     // 524288 u16
    u16*   protosT   = (u16*)(w + 1362560);     // 524288 u16
    u16*   gwT       = (u16*)(w + 1624704);     // 2,097,152 u16 -> ends 2,673,280
    u16*   attn_bf   = (u16*)(w + 2673280);     // 3,211,264 u16 -> ends 4,278,912
    u16*   Abig      = (u16*)(w + 4278912);     // [6272][2048] u16 -> ends 10,701,440
    u16*   A_cls     = (u16*)(w + 2673280);     // [4][1600][2048] u16 -> ends 9,226,880;
                                                //   overlay attn_bf+Abig (written at
                                                //   im2col, after all readers done)
    float* dots      = w + 10701440;            // 3,211,264 (dead after softmax)
    u16*   partial   = (u16*)(w + 4278912);     // bf16 [16][32][25088] = 12,845,056 u16
                                                //   -> ends 10,701,440; overlays Abig
                                                //   (dead after gate GEMM); read by
                                                //   dec_reduce BEFORE im2col writes A_cls
    u16*   h2cb      = (u16*)(w + 11364992);    // bf16 [6272][256] -> ends 12,970,624
    u16*   hp        = (u16*)(w + 17123968);    // zero-padded h buffer -> ends 17,787,520
    float* G         = w + 17787520;            // [6272][64] fp32 -> ends 18,188,928
    u16*   wpad      = (u16*)(w + 18188928);    // [64][256] bf16 -> ends 18,197,120 (72.8MB)

    // merged prep: hp zero + ct1 wtrans + ct2 wpad + pooled zero
    prep_kernel<<<1256, 256, 0, stream>>>(hp, ct1_w, wt1bf, ct2_w, wpad, pooled);
    // fused norm + bf16 cvt (z -> Abig left half; protos -> protos_bf)
    norm_cvt_kernel<<<6272, 256, 0, stream>>>(z, Abig, 2048, zn);
    norm_cvt_kernel<<<512, 256, 0, stream>>>(protos, protos_bf, 1024, pn);
    transpose_cvt_kernel<<<dim3(16, 8), 256, 0, stream>>>(protos, protosT, 512, 1024);
    transpose_cvt_kernel<<<dim3(16, 32), 256, 0, stream>>>(gate_w, gwT, 2048, 1024);
    // dots = z @ protos^T (M=6272, N=512, K=1024), 64x128 tiles, XCD swizzle
    mfma_gemm_kernel<2, 4, 0, true><<<dim3(98, 4), 256, 0, stream>>>(
        Abig, 2048, 0, protos_bf, 1024, 0, 6272, 512, 1024,
        dots, nullptr, 0, nullptr, nullptr, nullptr, 0, nullptr);
    // softmax -> attn (fp32 out) + attn_bf
    softmax_kernel<<<6272, 256, 0, stream>>>(dots, zn, pn, attn, attn_bf);
    // z_hat = attn @ protos (M=6272, N=1024, K=512), 64x128 tiles -> 784 blocks
    mfma_gemm_kernel<2, 4, 1, true><<<dim3(98, 8), 256, 0, stream>>>(
        attn_bf, 512, 0, protosT, 512, 0, 6272, 1024, 512,
        nullptr, Abig + 1024, 2048, nullptr, nullptr, nullptr, 0, nullptr);
    // gate GEMM (K=2048) + sigmoid blend + fused pooling, 64x128 -> 784 blocks
    mfma_gemm_kernel<2, 4, 2, true><<<dim3(98, 8), 256, 0, stream>>>(
        Abig, 2048, 0, gwT, 2048, 0, 6272, 1024, 2048,
        nullptr, nullptr, 0, gate_b, Abig, Abig + 1024, 2048, pooled);
    // decoder (split-K streaming GEMV, bf16 partials, load-batch pipeline)
    dec_split_kernel<<<dim3(98, 16), 256, 0, stream>>>(pooled, dec_w, partial);
    dec_reduce_kernel<<<dim3(49, 32), 256, 0, stream>>>(partial, dec_b, hp);
    // convT1 as grouped MFMA GEMM, 32x64 tiles -> 800 blocks
    im2col_kernel<<<6400, 256, 0, stream>>>(hp, A_cls);
    mfma_gemm_kernel<1, 2, 3, false><<<dim3(50, 4, 4), 256, 0, stream>>>(
        A_cls, 2048, (size_t)1600 * 2048, wt1bf, 2048, (size_t)256 * 2048,
        1600, 256, 2048, nullptr, h2cb, 0, ct1_b, nullptr, nullptr, 0, nullptr);
    // convT2 as GEMM (M=6272, N=64, K=256), 32x64 tiles -> 196 blocks
    mfma_gemm_kernel<1, 2, 0, false><<<dim3(196, 1), 256, 0, stream>>>(
        h2cb, 256, 0, wpad, 256, 0, 6272, 64, 256,
        G, nullptr, 0, nullptr, nullptr, nullptr, 0, nullptr);
    convt2_gather_kernel<<<294, 256, 0, stream>>>(G, ct2_b, xout);
}

// Round 13
// 203.514 us; speedup vs baseline: 1.0664x; 1.0664x over previous
//
#include <hip/hip_runtime.h>
#include <cstdint>
#include <cstddef>
#include <cmath>

#define EPS_COS 1e-8f

typedef unsigned short u16;
typedef __attribute__((ext_vector_type(8))) short short8v;
typedef __attribute__((ext_vector_type(4))) short short4v;
typedef __attribute__((ext_vector_type(4))) float f32x4;

__device__ __forceinline__ u16 f2bf(float x) {
    unsigned int u = __float_as_uint(x);
    return (u16)((u + 0x7FFFu + ((u >> 16) & 1u)) >> 16);  // RNE
}
__device__ __forceinline__ float bf2f(u16 h) {
    return __uint_as_float(((unsigned int)h) << 16);
}

// ---------------------------------------------------------------------------
// fused row L2 norm + bf16 convert (C fixed = 1024), one block per row
// ---------------------------------------------------------------------------
__global__ __launch_bounds__(256) void norm_cvt_kernel(const float* __restrict__ src,
                                                       u16* __restrict__ dst, int dstStride,
                                                       float* __restrict__ norms) {
    int r = blockIdx.x;
    int t = threadIdx.x;
    const float4 v = *reinterpret_cast<const float4*>(&src[(size_t)r * 1024 + t * 4]);
    short4v o;
    o[0] = f2bf(v.x); o[1] = f2bf(v.y); o[2] = f2bf(v.z); o[3] = f2bf(v.w);
    *reinterpret_cast<short4v*>(&dst[(size_t)r * dstStride + t * 4]) = o;
    float ss = v.x * v.x + v.y * v.y + v.z * v.z + v.w * v.w;
#pragma unroll
    for (int off = 32; off > 0; off >>= 1) ss += __shfl_down(ss, off);
    __shared__ float red[4];
    int wave = t >> 6, lane = t & 63;
    if (lane == 0) red[wave] = ss;
    __syncthreads();
    if (t == 0) norms[r] = sqrtf(red[0] + red[1] + red[2] + red[3]);
}

// ---------------------------------------------------------------------------
// transpose + cvt: src [R][C] f32 -> dst [C][R] bf16 (64x64 LDS tiles, +1 pad)
// ---------------------------------------------------------------------------
__global__ __launch_bounds__(256) void transpose_cvt_kernel(const float* __restrict__ src,
                                                            u16* __restrict__ dst,
                                                            int R, int C) {
    __shared__ float tile[64][65];
    int c0 = blockIdx.x * 64, r0 = blockIdx.y * 64;
    int t = threadIdx.x;
#pragma unroll
    for (int j = 0; j < 16; ++j) {
        int idx = j * 256 + t;
        int r = idx >> 6, c = idx & 63;
        tile[r][c] = src[(size_t)(r0 + r) * C + c0 + c];
    }
    __syncthreads();
#pragma unroll
    for (int j = 0; j < 16; ++j) {
        int idx = j * 256 + t;
        int c = idx >> 6, r = idx & 63;
        dst[(size_t)(c0 + c) * R + r0 + r] = f2bf(tile[r][c]);
    }
}

// ---------------------------------------------------------------------------
// merged prep: [0,165888) zero hp; [..+131072) ct1_w -> wt1bf;
// [..+16384) ct2_w -> wpad; [..+8192) zero pooled. 1256 blocks x 256.
// ---------------------------------------------------------------------------
__global__ __launch_bounds__(256) void prep_kernel(u16* __restrict__ hp,
                                                   const float* __restrict__ ct1w,
                                                   u16* __restrict__ wt,
                                                   const float* __restrict__ ct2w,
                                                   u16* __restrict__ wpad,
                                                   float* __restrict__ pooled) {
    int idx = blockIdx.x * 256 + threadIdx.x;
    if (idx < 165888) {
        short8v zv = {0, 0, 0, 0, 0, 0, 0, 0};
        *reinterpret_cast<short8v*>(hp + (size_t)idx * 8) = zv;
    } else if (idx < 165888 + 131072) {
        int i = idx - 165888;  // ic*256+oc
        int oc = i & 255, ic = i >> 8;
        float v[16];
#pragma unroll
        for (int j = 0; j < 16; ++j) v[j] = ct1w[(size_t)i * 16 + j];
#pragma unroll
        for (int pp = 0; pp < 4; ++pp) {
            int py = pp >> 1, px = pp & 1;
#pragma unroll
            for (int tap = 0; tap < 4; ++tap) {
                int ty = tap >> 1, tx = tap & 1;
                int ky = (1 - py) + 2 * ty;
                int kx = (1 - px) + 2 * tx;
                wt[((size_t)(pp * 256 + oc)) * 2048 + ic * 4 + tap] = f2bf(v[ky * 4 + kx]);
            }
        }
    } else if (idx < 165888 + 131072 + 16384) {
        int i = idx - 165888 - 131072;
        int ic = i & 255;
        int col = i >> 8;
        float v = 0.0f;
        if (col < 48) {
            int kx = col & 3, ky = (col >> 2) & 3, oc = col >> 4;
            v = ct2w[((size_t)ic * 3 + oc) * 16 + ky * 4 + kx];
        }
        wpad[i] = f2bf(v);
    } else {
        int i = idx - 165888 - 131072 - 16384;  // < 8192
        *reinterpret_cast<f32x4*>(pooled + (size_t)i * 4) = (f32x4){0.f, 0.f, 0.f, 0.f};
    }
}

// ---------------------------------------------------------------------------
// bf16 MFMA GEMM, all-NT, BK=64 reg-staged: C = A[M,K] * B[N,K]^T
// blockIdx.z selects (A,B) via zsA/zsB. BM=FM*32, BN=FN*32; 4 waves (2x2).
// LDS: [row][64 k] bf16; 16B chunk c stored at slot c^(row&7) (8-way XOR ->
// ds_read 2-way aliasing = free). SWZ: XCD-aware flat remap (nwg%8==0 only).
// EPI 0: fp32 store Cf[M][N]
// EPI 1: bf16 store Cb[row*sCb+col]
// EPI 2: g=sigmoid(acc+bias[col]); fused = g*z + (1-g)*z_hat (BOTH bf16 from
//        zbf/zhbf, stride szh); atomicAdd per-(batch,col) into outf (pooled)
// EPI 3: relu(acc+bias[col]) -> bf16 Cb[((b*4+z)*49+s)*256+col], row<1568
// ---------------------------------------------------------------------------
template <int FM, int FN, int EPI, bool SWZ>
__global__ __launch_bounds__(256) void mfma_gemm_kernel(
    const u16* __restrict__ A, int sA, size_t zsA,
    const u16* __restrict__ B, int sB, size_t zsB,
    int M, int N, int K,
    float* __restrict__ Cf,
    u16* __restrict__ Cb, int sCb,
    const float* __restrict__ bias,
    const u16* __restrict__ zbf,
    const u16* __restrict__ zhbf, int szh,
    float* __restrict__ outf) {
    constexpr int BM = FM * 32, BN = FN * 32;
    constexpr int NA = BM / 32;  // short8 chunks per thread (A), BK=64
    constexpr int NB = BN / 32;
    __shared__ __align__(16) u16 As[BM * 64];
    __shared__ __align__(16) u16 Bs[BN * 64];
    int bx = blockIdx.x, by = blockIdx.y;
    if (SWZ) {
        int gx = gridDim.x;
        int nwg = gx * gridDim.y;
        int lb = by * gx + bx;
        int flat = (lb & 7) * (nwg >> 3) + (lb >> 3);
        bx = flat % gx;
        by = flat / gx;
    }
    A += (size_t)blockIdx.z * zsA;
    B += (size_t)blockIdx.z * zsB;
    const int t = threadIdx.x;
    const int lane = t & 63;
    const int wid = t >> 6;
    const int wm = wid >> 1, wn = wid & 1;
    const int m0 = bx * BM, n0 = by * BN;
    const int g = lane >> 4, lr = lane & 15;

    f32x4 acc[FM][FN];
#pragma unroll
    for (int i = 0; i < FM; ++i)
#pragma unroll
        for (int j = 0; j < FN; ++j) acc[i][j] = (f32x4){0.f, 0.f, 0.f, 0.f};

    short8v ra[NA], rb[NB];
#pragma unroll
    for (int j = 0; j < NA; ++j) {
        int c = j * 256 + t, row = c >> 3, ck = c & 7;
        ra[j] = *reinterpret_cast<const short8v*>(A + (size_t)(m0 + row) * sA + ck * 8);
    }
#pragma unroll
    for (int j = 0; j < NB; ++j) {
        int c = j * 256 + t, row = c >> 3, ck = c & 7;
        rb[j] = *reinterpret_cast<const short8v*>(B + (size_t)(n0 + row) * sB + ck * 8);
    }

    for (int k0 = 0; k0 < K; k0 += 64) {
        __syncthreads();
#pragma unroll
        for (int j = 0; j < NA; ++j) {
            int c = j * 256 + t, row = c >> 3, ck = c & 7;
            *reinterpret_cast<short8v*>(As + row * 64 + ((ck ^ (row & 7)) << 3)) = ra[j];
        }
#pragma unroll
        for (int j = 0; j < NB; ++j) {
            int c = j * 256 + t, row = c >> 3, ck = c & 7;
            *reinterpret_cast<short8v*>(Bs + row * 64 + ((ck ^ (row & 7)) << 3)) = rb[j];
        }
        __syncthreads();
        if (k0 + 64 < K) {  // prefetch next tile into regs, overlaps MFMA below
#pragma unroll
            for (int j = 0; j < NA; ++j) {
                int c = j * 256 + t, row = c >> 3, ck = c & 7;
                ra[j] = *reinterpret_cast<const short8v*>(A + (size_t)(m0 + row) * sA + k0 + 64 + ck * 8);
            }
#pragma unroll
            for (int j = 0; j < NB; ++j) {
                int c = j * 256 + t, row = c >> 3, ck = c & 7;
                rb[j] = *reinterpret_cast<const short8v*>(B + (size_t)(n0 + row) * sB + k0 + 64 + ck * 8);
            }
        }
#pragma unroll
        for (int kk = 0; kk < 2; ++kk) {
            short8v af[FM], bfr[FN];
#pragma unroll
            for (int fm = 0; fm < FM; ++fm) {
                int row = wm * (FM * 16) + fm * 16 + lr;
                int rc = (kk * 4 + g) ^ (row & 7);
                af[fm] = *reinterpret_cast<const short8v*>(As + row * 64 + rc * 8);
            }
#pragma unroll
            for (int fn = 0; fn < FN; ++fn) {
                int col = wn * (FN * 16) + fn * 16 + lr;
                int rc = (kk * 4 + g) ^ (col & 7);
                bfr[fn] = *reinterpret_cast<const short8v*>(Bs + col * 64 + rc * 8);
            }
#pragma unroll
            for (int fm = 0; fm < FM; ++fm)
#pragma unroll
                for (int fn = 0; fn < FN; ++fn)
                    acc[fm][fn] = __builtin_amdgcn_mfma_f32_16x16x32_bf16(
                        af[fm], bfr[fn], acc[fm][fn], 0, 0, 0);
        }
    }

    if (EPI == 2) {
        // gate + blend (both operands bf16, resident rows of Abig) + pool
#pragma unroll
        for (int fn = 0; fn < FN; ++fn) {
            int col = n0 + wn * (FN * 16) + fn * 16 + lr;
            int base = m0 + wm * (FM * 16) + g * 4;
            int b0 = base / 196;
            float p0 = 0.f, p1 = 0.f;
#pragma unroll
            for (int fm = 0; fm < FM; ++fm) {
#pragma unroll
                for (int r = 0; r < 4; ++r) {
                    int row = base + fm * 16 + r;
                    float v = acc[fm][fn][r];
                    float gs = 1.0f / (1.0f + __expf(-(v + bias[col])));
                    float zv = bf2f(zbf[(size_t)row * szh + col]);
                    float zh = bf2f(zhbf[(size_t)row * szh + col]);
                    float fused = gs * zv + (1.0f - gs) * zh;
                    bool same = (row / 196) == b0;
                    p0 += same ? fused : 0.f;
                    p1 += same ? 0.f : fused;
                }
            }
            atomicAdd(&outf[(size_t)b0 * 1024 + col], p0);
            if (p1 != 0.f) atomicAdd(&outf[(size_t)(b0 + 1) * 1024 + col], p1);
        }
    } else {
#pragma unroll
        for (int fm = 0; fm < FM; ++fm) {
#pragma unroll
            for (int fn = 0; fn < FN; ++fn) {
#pragma unroll
                for (int r = 0; r < 4; ++r) {
                    int row = m0 + wm * (FM * 16) + fm * 16 + g * 4 + r;
                    int col = n0 + wn * (FN * 16) + fn * 16 + lr;
                    float v = acc[fm][fn][r];
                    if (EPI == 0) {
                        Cf[(size_t)row * N + col] = v;
                    } else if (EPI == 1) {
                        Cb[(size_t)row * sCb + col] = f2bf(v);
                    } else {  // EPI == 3
                        if (row < 1568) {
                            float vv = fmaxf(v + bias[col], 0.0f);
                            int bb = row / 49, ss = row - bb * 49;
                            Cb[(((size_t)bb * 4 + blockIdx.z) * 49 + ss) * 256 + col] = f2bf(vv);
                        }
                    }
                }
            }
        }
    }
}

// ---------------------------------------------------------------------------
// softmax over K=512 with cosine scaling; writes attn (fp32, d_out) + bf16 copy
// ---------------------------------------------------------------------------
__global__ __launch_bounds__(256) void softmax_kernel(const float* __restrict__ dots,
                                                      const float* __restrict__ zn,
                                                      const float* __restrict__ pn,
                                                      float* __restrict__ attn,
                                                      u16* __restrict__ attn_bf) {
    int m = blockIdx.x;
    int t = threadIdx.x;
    float zm = zn[m];
    float d0 = dots[(size_t)m * 512 + t];
    float d1 = dots[(size_t)m * 512 + t + 256];
    float v0 = d0 / fmaxf(zm * pn[t], EPS_COS);
    float v1 = d1 / fmaxf(zm * pn[t + 256], EPS_COS);
    float mx = fmaxf(v0, v1);
#pragma unroll
    for (int off = 32; off > 0; off >>= 1) mx = fmaxf(mx, __shfl_down(mx, off));
    __shared__ float red[8];
    int wave = t >> 6, lane = t & 63;
    if (lane == 0) red[wave] = mx;
    __syncthreads();
    if (t == 0) red[4] = fmaxf(fmaxf(red[0], red[1]), fmaxf(red[2], red[3]));
    __syncthreads();
    mx = red[4];
    float e0 = expf(v0 - mx), e1 = expf(v1 - mx);
    float s = e0 + e1;
#pragma unroll
    for (int off = 32; off > 0; off >>= 1) s += __shfl_down(s, off);
    if (lane == 0) red[wave] = s;
    __syncthreads();
    if (t == 0) red[5] = 1.0f / (red[0] + red[1] + red[2] + red[3]);
    __syncthreads();
    float r = red[5];
    float a0 = e0 * r, a1 = e1 * r;
    attn[(size_t)m * 512 + t] = a0;
    attn[(size_t)m * 512 + t + 256] = a1;
    attn_bf[(size_t)m * 512 + t] = f2bf(a0);
    attn_bf[(size_t)m * 512 + t + 256] = f2bf(a1);
}

// ---------------------------------------------------------------------------
// dec split-K phase 1: partial[kc][b][c] = sum_{k in 64-chunk} pooled[b][k]*W[k][c]
// grid (98,16). Load-batch idiom (8 f32x4 loads before any use) + bf16 partials
// — the r12-measured config (dec_split left the top-5).
// ---------------------------------------------------------------------------
#define DEC_KC 64
__global__ __launch_bounds__(256) void dec_split_kernel(const float* __restrict__ pooled,
                                                        const float* __restrict__ dec_w,
                                                        u16* __restrict__ partial) {
    const int t = threadIdx.x;
    const int lane = t & 63;
    const int wv = t >> 6;  // 0..3
    const int c = blockIdx.x * 256 + lane * 4;
    const int kc = blockIdx.y;
    __shared__ float pl[32][DEC_KC];
    for (int i = t; i < 32 * DEC_KC; i += 256) {
        int b = i >> 6, kk = i & (DEC_KC - 1);
        pl[b][kk] = pooled[(size_t)b * 1024 + kc * DEC_KC + kk] * (1.0f / 196.0f);
    }
    __syncthreads();
    f32x4 acc[8];
#pragma unroll
    for (int j = 0; j < 8; ++j) acc[j] = (f32x4){0.f, 0.f, 0.f, 0.f};
    const float* wp = dec_w + (size_t)(kc * DEC_KC) * 25088 + c;
#pragma unroll 1
    for (int k = 0; k < DEC_KC; k += 8) {
        f32x4 wv8[8];
#pragma unroll
        for (int q = 0; q < 8; ++q)
            wv8[q] = *reinterpret_cast<const f32x4*>(wp + (size_t)(k + q) * 25088);
#pragma unroll
        for (int q = 0; q < 8; ++q) {
#pragma unroll
            for (int j = 0; j < 8; ++j) {
                float pv = pl[wv * 8 + j][k + q];
                acc[j].x = fmaf(pv, wv8[q].x, acc[j].x);
                acc[j].y = fmaf(pv, wv8[q].y, acc[j].y);
                acc[j].z = fmaf(pv, wv8[q].z, acc[j].z);
                acc[j].w = fmaf(pv, wv8[q].w, acc[j].w);
            }
        }
    }
#pragma unroll
    for (int j = 0; j < 8; ++j) {
        int b = wv * 8 + j;
        short4v o;
        o[0] = f2bf(acc[j].x); o[1] = f2bf(acc[j].y);
        o[2] = f2bf(acc[j].z); o[3] = f2bf(acc[j].w);
        *reinterpret_cast<short4v*>(partial + ((size_t)kc * 32 + b) * 25088 + c) = o;
    }
}

// ---------------------------------------------------------------------------
// dec split-K phase 2: h[b][c] = sum_{kc<16} bf16 partial + dec_b[c] -> bf16 hp
// ---------------------------------------------------------------------------
__global__ __launch_bounds__(256) void dec_reduce_kernel(const u16* __restrict__ partial,
                                                         const float* __restrict__ dec_b,
                                                         u16* __restrict__ hp) {
    int c = (blockIdx.x * 256 + threadIdx.x) * 2;
    int b = blockIdx.y;
    float2 bb = *reinterpret_cast<const float2*>(&dec_b[c]);
    float s0 = bb.x, s1 = bb.y;
#pragma unroll
    for (int kc = 0; kc < 16; ++kc) {
        unsigned int v = *reinterpret_cast<const unsigned int*>(
            partial + ((size_t)kc * 32 + b) * 25088 + c);
        s0 += bf2f((u16)(v & 0xffffu));
        s1 += bf2f((u16)(v >> 16));
    }
#pragma unroll
    for (int q = 0; q < 2; ++q) {
        int cc = c + q;
        float s = q ? s1 : s0;
        int ic = cc / 49, sp = cc - ic * 49;
        int sy = sp / 7, sx = sp - sy * 7;
        hp[((size_t)b * 512 + ic) * 81 + (sy + 1) * 9 + sx + 1] = f2bf(s);
    }
}

// ---------------------------------------------------------------------------
// im2col for convT1 parity classes: A[p][row=b*49+s][k=ic*4+tap] bf16
// ---------------------------------------------------------------------------
__global__ __launch_bounds__(256) void im2col_kernel(const u16* __restrict__ hp,
                                                     u16* __restrict__ A) {
    int idx = blockIdx.x * 256 + threadIdx.x;  // < 1,638,400
    int k8 = idx & 255;                        // 8 cols = 2 ic x 4 taps
    int pr = idx >> 8;
    int p = pr / 1600;
    int row = pr - p * 1600;
    short8v o = {0, 0, 0, 0, 0, 0, 0, 0};
    if (row < 1568) {
        int b = row / 49, s = row - b * 49;
        int sy = s / 7, sx = s - sy * 7;
        int r0 = sy + (p >> 1) + 1;
        int c0 = sx + (p & 1) + 1;
        int ic0 = k8 * 2;
        const u16* hb = hp + ((size_t)b * 512 + ic0) * 81;
#pragma unroll
        for (int j = 0; j < 2; ++j) {
            o[j * 4 + 0] = hb[r0 * 9 + c0];
            o[j * 4 + 1] = hb[r0 * 9 + c0 - 1];
            o[j * 4 + 2] = hb[(r0 - 1) * 9 + c0];
            o[j * 4 + 3] = hb[(r0 - 1) * 9 + c0 - 1];
            hb += 81;
        }
    }
    *reinterpret_cast<short8v*>(A + (size_t)idx * 8) = o;
}

// ---------------------------------------------------------------------------
// convT2 gather: out[o] = bias[oc] + sum_{<=4 taps} G[row][oc*16+ky*4+kx]
// ---------------------------------------------------------------------------
__global__ __launch_bounds__(256) void convt2_gather_kernel(const float* __restrict__ G,
                                                            const float* __restrict__ bias,
                                                            float* __restrict__ out) {
    int o = blockIdx.x * 256 + threadIdx.x;  // < 75264
    int ox = o % 28;
    int oy = (o / 28) % 28;
    int oc = (o / 784) % 3;
    int b = o / 2352;
    int by = (oy + 1) >> 1, bx = (ox + 1) >> 1;
    float acc = bias[oc];
#pragma unroll
    for (int ty = 0; ty < 2; ++ty) {
        int iy = by - ty;
        if ((unsigned)iy >= 14u) continue;
#pragma unroll
        for (int tx = 0; tx < 2; ++tx) {
            int ix = bx - tx;
            if ((unsigned)ix >= 14u) continue;
            int p = (iy & 1) * 2 + (ix & 1);
            int row = ((b * 4 + p) * 49) + (iy >> 1) * 7 + (ix >> 1);
            int ky = oy + 1 - 2 * iy, kx = ox + 1 - 2 * ix;
            acc += G[(size_t)row * 64 + oc * 16 + ky * 4 + kx];
        }
    }
    out[o] = acc;
}

// ---------------------------------------------------------------------------
extern "C" void kernel_launch(void* const* d_in, const int* in_sizes, int n_in,
                              void* d_out, int out_size, void* d_ws, size_t ws_size,
                              hipStream_t stream) {
    const float* z      = (const float*)d_in[0];  // [32,196,1024]
    const float* protos = (const float*)d_in[1];  // [512,1024]
    const float* gate_w = (const float*)d_in[2];  // [2048,1024]
    const float* gate_b = (const float*)d_in[3];  // [1024]
    const float* dec_w  = (const float*)d_in[4];  // [1024,25088]
    const float* dec_b  = (const float*)d_in[5];  // [25088]
    const float* ct1_w  = (const float*)d_in[6];  // [512,256,4,4]
    const float* ct1_b  = (const float*)d_in[7];  // [256]
    const float* ct2_w  = (const float*)d_in[8];  // [256,3,4,4]
    const float* ct2_b  = (const float*)d_in[9];  // [3]

    float* xout = (float*)d_out;   // x_recon 75264
    float* attn = xout + 75264;    // attn 3211264

    float* w = (float*)d_ws;
    float* pn        = w;                       // 512
    float* zn        = w + 512;                 // 6272
    float* pooled    = w + 6784;                // 32768 (atomic-accumulated token sums)
    u16*   wt1bf     = (u16*)(w + 51840);       // 2,097,152 u16 -> ends 1,100,416
    u16*   protos_bf = (u16*)(w + 1100416);     // 524288 u16
    u16*   protosT   = (u16*)(w + 1362560);     // 524288 u16
    u16*   gwT       = (u16*)(w + 1624704);     // 2,097,152 u16 -> ends 2,673,280
    u16*   attn_bf   = (u16*)(w + 2673280);     // 3,211,264 u16 -> ends 4,278,912
    u16*   Abig      = (u16*)(w + 4278912);     // [6272][2048] u16 -> ends 10,701,440
    u16*   A_cls     = (u16*)(w + 2673280);     // [4][1600][2048] u16 -> ends 9,226,880;
                                                //   overlay attn_bf+Abig (written at
                                                //   im2col, after all readers done)
    float* dots      = w + 10701440;            // 3,211,264 (dead after softmax)
    u16*   partial   = (u16*)(w + 4278912);     // bf16 [16][32][25088] overlays Abig
                                                //   (dead after gate GEMM); read by
                                                //   dec_reduce BEFORE im2col writes A_cls
    u16*   h2cb      = (u16*)(w + 11364992);    // bf16 [6272][256] -> ends 12,970,624
    u16*   hp        = (u16*)(w + 17123968);    // zero-padded h buffer -> ends 17,787,520
    float* G         = w + 17787520;            // [6272][64] fp32 -> ends 18,188,928
    u16*   wpad      = (u16*)(w + 18188928);    // [64][256] bf16 -> ends 18,197,120 (72.8MB)

    // merged prep: hp zero + ct1 wtrans + ct2 wpad + pooled zero
    prep_kernel<<<1256, 256, 0, stream>>>(hp, ct1_w, wt1bf, ct2_w, wpad, pooled);
    // fused norm + bf16 cvt (z -> Abig left half; protos -> protos_bf)
    norm_cvt_kernel<<<6272, 256, 0, stream>>>(z, Abig, 2048, zn);
    norm_cvt_kernel<<<512, 256, 0, stream>>>(protos, protos_bf, 1024, pn);
    transpose_cvt_kernel<<<dim3(16, 8), 256, 0, stream>>>(protos, protosT, 512, 1024);
    transpose_cvt_kernel<<<dim3(16, 32), 256, 0, stream>>>(gate_w, gwT, 2048, 1024);
    // dots = z @ protos^T (M=6272, N=512, K=1024), 64x128 tiles, XCD swizzle
    mfma_gemm_kernel<2, 4, 0, true><<<dim3(98, 4), 256, 0, stream>>>(
        Abig, 2048, 0, protos_bf, 1024, 0, 6272, 512, 1024,
        dots, nullptr, 0, nullptr, nullptr, nullptr, 0, nullptr);
    // softmax -> attn (fp32 out) + attn_bf
    softmax_kernel<<<6272, 256, 0, stream>>>(dots, zn, pn, attn, attn_bf);
    // z_hat = attn @ protos (M=6272, N=1024, K=512), 128x128 tiles (r11 best)
    mfma_gemm_kernel<4, 4, 1, true><<<dim3(49, 8), 256, 0, stream>>>(
        attn_bf, 512, 0, protosT, 512, 0, 6272, 1024, 512,
        nullptr, Abig + 1024, 2048, nullptr, nullptr, nullptr, 0, nullptr);
    // gate GEMM (K=2048) + sigmoid blend + fused pooling, 128x128 (r11 best)
    mfma_gemm_kernel<4, 4, 2, true><<<dim3(49, 8), 256, 0, stream>>>(
        Abig, 2048, 0, gwT, 2048, 0, 6272, 1024, 2048,
        nullptr, nullptr, 0, gate_b, Abig, Abig + 1024, 2048, pooled);
    // decoder (split-K streaming GEMV, bf16 partials, load-batch — r12 best)
    dec_split_kernel<<<dim3(98, 16), 256, 0, stream>>>(pooled, dec_w, partial);
    dec_reduce_kernel<<<dim3(49, 32), 256, 0, stream>>>(partial, dec_b, hp);
    // convT1 as grouped MFMA GEMM, 32x64 tiles -> 800 blocks (r12)
    im2col_kernel<<<6400, 256, 0, stream>>>(hp, A_cls);
    mfma_gemm_kernel<1, 2, 3, false><<<dim3(50, 4, 4), 256, 0, stream>>>(
        A_cls, 2048, (size_t)1600 * 2048, wt1bf, 2048, (size_t)256 * 2048,
        1600, 256, 2048, nullptr, h2cb, 0, ct1_b, nullptr, nullptr, 0, nullptr);
    // convT2 as GEMM (M=6272, N=64, K=256), 32x64 tiles -> 196 blocks (r12)
    mfma_gemm_kernel<1, 2, 0, false><<<dim3(196, 1), 256, 0, stream>>>(
        h2cb, 256, 0, wpad, 256, 0, 6272, 64, 256,
        G, nullptr, 0, nullptr, nullptr, nullptr, 0, nullptr);
    convt2_gather_kernel<<<294, 256, 0, stream>>>(G, ct2_b, xout);
}

// Round 14
// 189.600 us; speedup vs baseline: 1.1446x; 1.0734x over previous
//
#include <hip/hip_runtime.h>
#include <cstdint>
#include <cstddef>
#include <cmath>

#define EPS_COS 1e-8f

typedef unsigned short u16;
typedef __attribute__((ext_vector_type(8))) short short8v;
typedef __attribute__((ext_vector_type(4))) short short4v;
typedef __attribute__((ext_vector_type(4))) float f32x4;

__device__ __forceinline__ u16 f2bf(float x) {
    unsigned int u = __float_as_uint(x);
    return (u16)((u + 0x7FFFu + ((u >> 16) & 1u)) >> 16);  // RNE
}
__device__ __forceinline__ float bf2f(u16 h) {
    return __uint_as_float(((unsigned int)h) << 16);
}

// ---------------------------------------------------------------------------
// fused row L2 norm + bf16 convert (C fixed = 1024), one block per row
// ---------------------------------------------------------------------------
__global__ __launch_bounds__(256) void norm_cvt_kernel(const float* __restrict__ src,
                                                       u16* __restrict__ dst, int dstStride,
                                                       float* __restrict__ norms) {
    int r = blockIdx.x;
    int t = threadIdx.x;
    const float4 v = *reinterpret_cast<const float4*>(&src[(size_t)r * 1024 + t * 4]);
    short4v o;
    o[0] = f2bf(v.x); o[1] = f2bf(v.y); o[2] = f2bf(v.z); o[3] = f2bf(v.w);
    *reinterpret_cast<short4v*>(&dst[(size_t)r * dstStride + t * 4]) = o;
    float ss = v.x * v.x + v.y * v.y + v.z * v.z + v.w * v.w;
#pragma unroll
    for (int off = 32; off > 0; off >>= 1) ss += __shfl_down(ss, off);
    __shared__ float red[4];
    int wave = t >> 6, lane = t & 63;
    if (lane == 0) red[wave] = ss;
    __syncthreads();
    if (t == 0) norms[r] = sqrtf(red[0] + red[1] + red[2] + red[3]);
}

// ---------------------------------------------------------------------------
// transpose + cvt: src [R][C] f32 -> dst [C][R] bf16 (64x64 LDS tiles, +1 pad)
// ---------------------------------------------------------------------------
__global__ __launch_bounds__(256) void transpose_cvt_kernel(const float* __restrict__ src,
                                                            u16* __restrict__ dst,
                                                            int R, int C) {
    __shared__ float tile[64][65];
    int c0 = blockIdx.x * 64, r0 = blockIdx.y * 64;
    int t = threadIdx.x;
#pragma unroll
    for (int j = 0; j < 16; ++j) {
        int idx = j * 256 + t;
        int r = idx >> 6, c = idx & 63;
        tile[r][c] = src[(size_t)(r0 + r) * C + c0 + c];
    }
    __syncthreads();
#pragma unroll
    for (int j = 0; j < 16; ++j) {
        int idx = j * 256 + t;
        int c = idx >> 6, r = idx & 63;
        dst[(size_t)(c0 + c) * R + r0 + r] = f2bf(tile[r][c]);
    }
}

// ---------------------------------------------------------------------------
// merged prep: [0,165888) zero hp; [..+131072) ct1_w -> wt1bf;
// [..+16384) ct2_w -> wpad; [..+8192) zero pooled. 1256 blocks x 256.
// ---------------------------------------------------------------------------
__global__ __launch_bounds__(256) void prep_kernel(u16* __restrict__ hp,
                                                   const float* __restrict__ ct1w,
                                                   u16* __restrict__ wt,
                                                   const float* __restrict__ ct2w,
                                                   u16* __restrict__ wpad,
                                                   float* __restrict__ pooled) {
    int idx = blockIdx.x * 256 + threadIdx.x;
    if (idx < 165888) {
        short8v zv = {0, 0, 0, 0, 0, 0, 0, 0};
        *reinterpret_cast<short8v*>(hp + (size_t)idx * 8) = zv;
    } else if (idx < 165888 + 131072) {
        int i = idx - 165888;  // ic*256+oc
        int oc = i & 255, ic = i >> 8;
        float v[16];
#pragma unroll
        for (int j = 0; j < 16; ++j) v[j] = ct1w[(size_t)i * 16 + j];
#pragma unroll
        for (int pp = 0; pp < 4; ++pp) {
            int py = pp >> 1, px = pp & 1;
#pragma unroll
            for (int tap = 0; tap < 4; ++tap) {
                int ty = tap >> 1, tx = tap & 1;
                int ky = (1 - py) + 2 * ty;
                int kx = (1 - px) + 2 * tx;
                wt[((size_t)(pp * 256 + oc)) * 2048 + ic * 4 + tap] = f2bf(v[ky * 4 + kx]);
            }
        }
    } else if (idx < 165888 + 131072 + 16384) {
        int i = idx - 165888 - 131072;
        int ic = i & 255;
        int col = i >> 8;
        float v = 0.0f;
        if (col < 48) {
            int kx = col & 3, ky = (col >> 2) & 3, oc = col >> 4;
            v = ct2w[((size_t)ic * 3 + oc) * 16 + ky * 4 + kx];
        }
        wpad[i] = f2bf(v);
    } else {
        int i = idx - 165888 - 131072 - 16384;  // < 8192
        *reinterpret_cast<f32x4*>(pooled + (size_t)i * 4) = (f32x4){0.f, 0.f, 0.f, 0.f};
    }
}

// ---------------------------------------------------------------------------
// bf16 MFMA GEMM, all-NT, BK=64 reg-staged: C = A[M,K] * B[N,K]^T
// blockIdx.z selects (A,B) via zsA/zsB. BM=FM*32, BN=FN*32; 4 waves (2x2).
// LDS: [row][64 k] bf16; 16B chunk c stored at slot c^(row&7) (8-way XOR ->
// ds_read 2-way aliasing = free). SWZ: XCD-aware flat remap (nwg%8==0 only).
// EPI 0: fp32 store Cf[M][N]
// EPI 1: bf16 store Cb[row*sCb+col]
// EPI 2: g=sigmoid(acc+bias[col]); fused = g*z + (1-g)*z_hat (BOTH bf16 from
//        zbf/zhbf, stride szh); atomicAdd per-(batch,col) into outf (pooled)
// EPI 3: relu(acc+bias[col]) -> bf16 Cb[((b*4+z)*49+s)*256+col], row<1568
// ---------------------------------------------------------------------------
template <int FM, int FN, int EPI, bool SWZ>
__global__ __launch_bounds__(256) void mfma_gemm_kernel(
    const u16* __restrict__ A, int sA, size_t zsA,
    const u16* __restrict__ B, int sB, size_t zsB,
    int M, int N, int K,
    float* __restrict__ Cf,
    u16* __restrict__ Cb, int sCb,
    const float* __restrict__ bias,
    const u16* __restrict__ zbf,
    const u16* __restrict__ zhbf, int szh,
    float* __restrict__ outf) {
    constexpr int BM = FM * 32, BN = FN * 32;
    constexpr int NA = BM / 32;  // short8 chunks per thread (A), BK=64
    constexpr int NB = BN / 32;
    __shared__ __align__(16) u16 As[BM * 64];
    __shared__ __align__(16) u16 Bs[BN * 64];
    int bx = blockIdx.x, by = blockIdx.y;
    if (SWZ) {
        int gx = gridDim.x;
        int nwg = gx * gridDim.y;
        int lb = by * gx + bx;
        int flat = (lb & 7) * (nwg >> 3) + (lb >> 3);
        bx = flat % gx;
        by = flat / gx;
    }
    A += (size_t)blockIdx.z * zsA;
    B += (size_t)blockIdx.z * zsB;
    const int t = threadIdx.x;
    const int lane = t & 63;
    const int wid = t >> 6;
    const int wm = wid >> 1, wn = wid & 1;
    const int m0 = bx * BM, n0 = by * BN;
    const int g = lane >> 4, lr = lane & 15;

    f32x4 acc[FM][FN];
#pragma unroll
    for (int i = 0; i < FM; ++i)
#pragma unroll
        for (int j = 0; j < FN; ++j) acc[i][j] = (f32x4){0.f, 0.f, 0.f, 0.f};

    short8v ra[NA], rb[NB];
#pragma unroll
    for (int j = 0; j < NA; ++j) {
        int c = j * 256 + t, row = c >> 3, ck = c & 7;
        ra[j] = *reinterpret_cast<const short8v*>(A + (size_t)(m0 + row) * sA + ck * 8);
    }
#pragma unroll
    for (int j = 0; j < NB; ++j) {
        int c = j * 256 + t, row = c >> 3, ck = c & 7;
        rb[j] = *reinterpret_cast<const short8v*>(B + (size_t)(n0 + row) * sB + ck * 8);
    }

    for (int k0 = 0; k0 < K; k0 += 64) {
        __syncthreads();
#pragma unroll
        for (int j = 0; j < NA; ++j) {
            int c = j * 256 + t, row = c >> 3, ck = c & 7;
            *reinterpret_cast<short8v*>(As + row * 64 + ((ck ^ (row & 7)) << 3)) = ra[j];
        }
#pragma unroll
        for (int j = 0; j < NB; ++j) {
            int c = j * 256 + t, row = c >> 3, ck = c & 7;
            *reinterpret_cast<short8v*>(Bs + row * 64 + ((ck ^ (row & 7)) << 3)) = rb[j];
        }
        __syncthreads();
        if (k0 + 64 < K) {  // prefetch next tile into regs, overlaps MFMA below
#pragma unroll
            for (int j = 0; j < NA; ++j) {
                int c = j * 256 + t, row = c >> 3, ck = c & 7;
                ra[j] = *reinterpret_cast<const short8v*>(A + (size_t)(m0 + row) * sA + k0 + 64 + ck * 8);
            }
#pragma unroll
            for (int j = 0; j < NB; ++j) {
                int c = j * 256 + t, row = c >> 3, ck = c & 7;
                rb[j] = *reinterpret_cast<const short8v*>(B + (size_t)(n0 + row) * sB + k0 + 64 + ck * 8);
            }
        }
#pragma unroll
        for (int kk = 0; kk < 2; ++kk) {
            short8v af[FM], bfr[FN];
#pragma unroll
            for (int fm = 0; fm < FM; ++fm) {
                int row = wm * (FM * 16) + fm * 16 + lr;
                int rc = (kk * 4 + g) ^ (row & 7);
                af[fm] = *reinterpret_cast<const short8v*>(As + row * 64 + rc * 8);
            }
#pragma unroll
            for (int fn = 0; fn < FN; ++fn) {
                int col = wn * (FN * 16) + fn * 16 + lr;
                int rc = (kk * 4 + g) ^ (col & 7);
                bfr[fn] = *reinterpret_cast<const short8v*>(Bs + col * 64 + rc * 8);
            }
#pragma unroll
            for (int fm = 0; fm < FM; ++fm)
#pragma unroll
                for (int fn = 0; fn < FN; ++fn)
                    acc[fm][fn] = __builtin_amdgcn_mfma_f32_16x16x32_bf16(
                        af[fm], bfr[fn], acc[fm][fn], 0, 0, 0);
        }
    }

    if (EPI == 2) {
        // gate + blend (both operands bf16, resident rows of Abig) + pool
#pragma unroll
        for (int fn = 0; fn < FN; ++fn) {
            int col = n0 + wn * (FN * 16) + fn * 16 + lr;
            int base = m0 + wm * (FM * 16) + g * 4;
            int b0 = base / 196;
            float p0 = 0.f, p1 = 0.f;
#pragma unroll
            for (int fm = 0; fm < FM; ++fm) {
#pragma unroll
                for (int r = 0; r < 4; ++r) {
                    int row = base + fm * 16 + r;
                    float v = acc[fm][fn][r];
                    float gs = 1.0f / (1.0f + __expf(-(v + bias[col])));
                    float zv = bf2f(zbf[(size_t)row * szh + col]);
                    float zh = bf2f(zhbf[(size_t)row * szh + col]);
                    float fused = gs * zv + (1.0f - gs) * zh;
                    bool same = (row / 196) == b0;
                    p0 += same ? fused : 0.f;
                    p1 += same ? 0.f : fused;
                }
            }
            atomicAdd(&outf[(size_t)b0 * 1024 + col], p0);
            if (p1 != 0.f) atomicAdd(&outf[(size_t)(b0 + 1) * 1024 + col], p1);
        }
    } else {
#pragma unroll
        for (int fm = 0; fm < FM; ++fm) {
#pragma unroll
            for (int fn = 0; fn < FN; ++fn) {
#pragma unroll
                for (int r = 0; r < 4; ++r) {
                    int row = m0 + wm * (FM * 16) + fm * 16 + g * 4 + r;
                    int col = n0 + wn * (FN * 16) + fn * 16 + lr;
                    float v = acc[fm][fn][r];
                    if (EPI == 0) {
                        Cf[(size_t)row * N + col] = v;
                    } else if (EPI == 1) {
                        Cb[(size_t)row * sCb + col] = f2bf(v);
                    } else {  // EPI == 3
                        if (row < 1568) {
                            float vv = fmaxf(v + bias[col], 0.0f);
                            int bb = row / 49, ss = row - bb * 49;
                            Cb[(((size_t)bb * 4 + blockIdx.z) * 49 + ss) * 256 + col] = f2bf(vv);
                        }
                    }
                }
            }
        }
    }
}

// ---------------------------------------------------------------------------
// decoder as one MFMA GEMM, B staged NN directly from fp32 dec_w (read ONCE,
// no transpose pass, no split-K partials):
// h[b][c] = (pooled[b][:]/196) @ dec_w[:,c] + dec_b[c] -> bf16 hp interior.
// M=32 (2 waves x 16 rows), BN=128 (2 wave-cols), BK=64, grid (196).
// LDS row stride 72 u16 = 144B (16B-aligned rows, near-conflict-free banks).
// B k-range XOR-swizzled in 16B chunks by ((n>>2)&3)<<3, same on write+read.
// ---------------------------------------------------------------------------
__global__ __launch_bounds__(256) void dec_gemm_kernel(const float* __restrict__ pooled,
                                                       const float* __restrict__ dec_w,
                                                       const float* __restrict__ dec_b,
                                                       u16* __restrict__ hp) {
    __shared__ __align__(16) u16 As[32 * 72];
    __shared__ __align__(16) u16 Bs[128 * 72];
    const int t = threadIdx.x;
    const int lane = t & 63;
    const int wid = t >> 6;
    const int wm = wid >> 1, wn = wid & 1;
    const int n0 = blockIdx.x * 128;
    const int g = lane >> 4, lr = lane & 15;

    // staging indices
    const int ar = t >> 3;                    // A row 0..31
    const int ak = (t & 7) * 8;               // A k-offset 0,8,..,56
    const int bn4 = (t & 31) * 4;             // B col base 0..124
    const int bk4 = (t >> 5) * 4;             // B k base 0..28 (+q*32)
    const int bswz = ((bn4 >> 2) & 3) << 3;   // 16B-chunk XOR (u16 units)
    const int bkp = (bk4 ^ bswz);             // swizzled k base (bits 3-4 only)

    f32x4 acc[4];
#pragma unroll
    for (int j = 0; j < 4; ++j) acc[j] = (f32x4){0.f, 0.f, 0.f, 0.f};

    f32x4 ra[2];
    f32x4 rb[2][4];
#pragma unroll
    for (int h = 0; h < 2; ++h)
        ra[h] = *reinterpret_cast<const f32x4*>(pooled + ar * 1024 + ak + h * 4);
#pragma unroll
    for (int q = 0; q < 2; ++q)
#pragma unroll
        for (int i = 0; i < 4; ++i)
            rb[q][i] = *reinterpret_cast<const f32x4*>(
                dec_w + (size_t)(bk4 + q * 32 + i) * 25088 + n0 + bn4);

    for (int k0 = 0; k0 < 1024; k0 += 64) {
        __syncthreads();  // prior iteration's frag reads complete
        {   // A: scale + cvt -> As[ar][ak..ak+8]
            short8v o;
#pragma unroll
            for (int h = 0; h < 2; ++h) {
                o[h * 4 + 0] = f2bf(ra[h].x * (1.0f / 196.0f));
                o[h * 4 + 1] = f2bf(ra[h].y * (1.0f / 196.0f));
                o[h * 4 + 2] = f2bf(ra[h].z * (1.0f / 196.0f));
                o[h * 4 + 3] = f2bf(ra[h].w * (1.0f / 196.0f));
            }
            *reinterpret_cast<short8v*>(As + ar * 72 + ak) = o;
        }
        // B: cvt + in-register 4x4 transpose -> Bs[n][k^swz]
#pragma unroll
        for (int q = 0; q < 2; ++q) {
#pragma unroll
            for (int j = 0; j < 4; ++j) {
                short4v o4;
                o4[0] = f2bf(rb[q][0][j]);
                o4[1] = f2bf(rb[q][1][j]);
                o4[2] = f2bf(rb[q][2][j]);
                o4[3] = f2bf(rb[q][3][j]);
                *reinterpret_cast<short4v*>(Bs + (bn4 + j) * 72 + bkp + q * 32) = o4;
            }
        }
        __syncthreads();
        if (k0 + 64 < 1024) {  // prefetch next K-tile (overlaps MFMA below)
#pragma unroll
            for (int h = 0; h < 2; ++h)
                ra[h] = *reinterpret_cast<const f32x4*>(
                    pooled + ar * 1024 + k0 + 64 + ak + h * 4);
#pragma unroll
            for (int q = 0; q < 2; ++q)
#pragma unroll
                for (int i = 0; i < 4; ++i)
                    rb[q][i] = *reinterpret_cast<const f32x4*>(
                        dec_w + (size_t)(k0 + 64 + bk4 + q * 32 + i) * 25088 + n0 + bn4);
        }
#pragma unroll
        for (int kk = 0; kk < 2; ++kk) {
            int row = wm * 16 + lr;
            short8v af = *reinterpret_cast<const short8v*>(As + row * 72 + kk * 32 + g * 8);
#pragma unroll
            for (int fn = 0; fn < 4; ++fn) {
                int col = wn * 64 + fn * 16 + lr;
                int ch = (kk * 32 + g * 8) ^ (((col >> 2) & 3) << 3);
                short8v bf8 = *reinterpret_cast<const short8v*>(Bs + col * 72 + ch);
                acc[fn] = __builtin_amdgcn_mfma_f32_16x16x32_bf16(af, bf8, acc[fn], 0, 0, 0);
            }
        }
    }
    // epilogue: h + dec_b -> hp[b][ic][9][9] interior (rows 0..31 all valid)
#pragma unroll
    for (int fn = 0; fn < 4; ++fn) {
#pragma unroll
        for (int r = 0; r < 4; ++r) {
            int row = wm * 16 + g * 4 + r;
            int col = n0 + wn * 64 + fn * 16 + lr;
            float v = acc[fn][r] + dec_b[col];
            int ic = col / 49, sp = col - ic * 49;
            int sy = sp / 7, sx = sp - sy * 7;
            hp[((size_t)row * 512 + ic) * 81 + (sy + 1) * 9 + sx + 1] = f2bf(v);
        }
    }
}

// ---------------------------------------------------------------------------
// softmax over K=512 with cosine scaling; writes attn (fp32, d_out) + bf16 copy
// ---------------------------------------------------------------------------
__global__ __launch_bounds__(256) void softmax_kernel(const float* __restrict__ dots,
                                                      const float* __restrict__ zn,
                                                      const float* __restrict__ pn,
                                                      float* __restrict__ attn,
                                                      u16* __restrict__ attn_bf) {
    int m = blockIdx.x;
    int t = threadIdx.x;
    float zm = zn[m];
    float d0 = dots[(size_t)m * 512 + t];
    float d1 = dots[(size_t)m * 512 + t + 256];
    float v0 = d0 / fmaxf(zm * pn[t], EPS_COS);
    float v1 = d1 / fmaxf(zm * pn[t + 256], EPS_COS);
    float mx = fmaxf(v0, v1);
#pragma unroll
    for (int off = 32; off > 0; off >>= 1) mx = fmaxf(mx, __shfl_down(mx, off));
    __shared__ float red[8];
    int wave = t >> 6, lane = t & 63;
    if (lane == 0) red[wave] = mx;
    __syncthreads();
    if (t == 0) red[4] = fmaxf(fmaxf(red[0], red[1]), fmaxf(red[2], red[3]));
    __syncthreads();
    mx = red[4];
    float e0 = expf(v0 - mx), e1 = expf(v1 - mx);
    float s = e0 + e1;
#pragma unroll
    for (int off = 32; off > 0; off >>= 1) s += __shfl_down(s, off);
    if (lane == 0) red[wave] = s;
    __syncthreads();
    if (t == 0) red[5] = 1.0f / (red[0] + red[1] + red[2] + red[3]);
    __syncthreads();
    float r = red[5];
    float a0 = e0 * r, a1 = e1 * r;
    attn[(size_t)m * 512 + t] = a0;
    attn[(size_t)m * 512 + t + 256] = a1;
    attn_bf[(size_t)m * 512 + t] = f2bf(a0);
    attn_bf[(size_t)m * 512 + t + 256] = f2bf(a1);
}

// ---------------------------------------------------------------------------
// im2col for convT1 parity classes: A[p][row=b*49+s][k=ic*4+tap] bf16
// ---------------------------------------------------------------------------
__global__ __launch_bounds__(256) void im2col_kernel(const u16* __restrict__ hp,
                                                     u16* __restrict__ A) {
    int idx = blockIdx.x * 256 + threadIdx.x;  // < 1,638,400
    int k8 = idx & 255;                        // 8 cols = 2 ic x 4 taps
    int pr = idx >> 8;
    int p = pr / 1600;
    int row = pr - p * 1600;
    short8v o = {0, 0, 0, 0, 0, 0, 0, 0};
    if (row < 1568) {
        int b = row / 49, s = row - b * 49;
        int sy = s / 7, sx = s - sy * 7;
        int r0 = sy + (p >> 1) + 1;
        int c0 = sx + (p & 1) + 1;
        int ic0 = k8 * 2;
        const u16* hb = hp + ((size_t)b * 512 + ic0) * 81;
#pragma unroll
        for (int j = 0; j < 2; ++j) {
            o[j * 4 + 0] = hb[r0 * 9 + c0];
            o[j * 4 + 1] = hb[r0 * 9 + c0 - 1];
            o[j * 4 + 2] = hb[(r0 - 1) * 9 + c0];
            o[j * 4 + 3] = hb[(r0 - 1) * 9 + c0 - 1];
            hb += 81;
        }
    }
    *reinterpret_cast<short8v*>(A + (size_t)idx * 8) = o;
}

// ---------------------------------------------------------------------------
// convT2 gather: out[o] = bias[oc] + sum_{<=4 taps} G[row][oc*16+ky*4+kx]
// ---------------------------------------------------------------------------
__global__ __launch_bounds__(256) void convt2_gather_kernel(const float* __restrict__ G,
                                                            const float* __restrict__ bias,
                                                            float* __restrict__ out) {
    int o = blockIdx.x * 256 + threadIdx.x;  // < 75264
    int ox = o % 28;
    int oy = (o / 28) % 28;
    int oc = (o / 784) % 3;
    int b = o / 2352;
    int by = (oy + 1) >> 1, bx = (ox + 1) >> 1;
    float acc = bias[oc];
#pragma unroll
    for (int ty = 0; ty < 2; ++ty) {
        int iy = by - ty;
        if ((unsigned)iy >= 14u) continue;
#pragma unroll
        for (int tx = 0; tx < 2; ++tx) {
            int ix = bx - tx;
            if ((unsigned)ix >= 14u) continue;
            int p = (iy & 1) * 2 + (ix & 1);
            int row = ((b * 4 + p) * 49) + (iy >> 1) * 7 + (ix >> 1);
            int ky = oy + 1 - 2 * iy, kx = ox + 1 - 2 * ix;
            acc += G[(size_t)row * 64 + oc * 16 + ky * 4 + kx];
        }
    }
    out[o] = acc;
}

// ---------------------------------------------------------------------------
extern "C" void kernel_launch(void* const* d_in, const int* in_sizes, int n_in,
                              void* d_out, int out_size, void* d_ws, size_t ws_size,
                              hipStream_t stream) {
    const float* z      = (const float*)d_in[0];  // [32,196,1024]
    const float* protos = (const float*)d_in[1];  // [512,1024]
    const float* gate_w = (const float*)d_in[2];  // [2048,1024]
    const float* gate_b = (const float*)d_in[3];  // [1024]
    const float* dec_w  = (const float*)d_in[4];  // [1024,25088]
    const float* dec_b  = (const float*)d_in[5];  // [25088]
    const float* ct1_w  = (const float*)d_in[6];  // [512,256,4,4]
    const float* ct1_b  = (const float*)d_in[7];  // [256]
    const float* ct2_w  = (const float*)d_in[8];  // [256,3,4,4]
    const float* ct2_b  = (const float*)d_in[9];  // [3]

    float* xout = (float*)d_out;   // x_recon 75264
    float* attn = xout + 75264;    // attn 3211264

    float* w = (float*)d_ws;
    float* pn        = w;                       // 512
    float* zn        = w + 512;                 // 6272
    float* pooled    = w + 6784;                // 32768 (atomic-accumulated token sums)
    u16*   wt1bf     = (u16*)(w + 51840);       // 2,097,152 u16 -> ends 1,100,416
    u16*   protos_bf = (u16*)(w + 1100416);     // 524288 u16
    u16*   protosT   = (u16*)(w + 1362560);     // 524288 u16
    u16*   gwT       = (u16*)(w + 1624704);     // 2,097,152 u16 -> ends 2,673,280
    u16*   attn_bf   = (u16*)(w + 2673280);     // 3,211,264 u16 -> ends 4,278,912
    u16*   Abig      = (u16*)(w + 4278912);     // [6272][2048] u16 -> ends 10,701,440
    u16*   A_cls     = (u16*)(w + 2673280);     // [4][1600][2048] u16 -> ends 9,226,880;
                                                //   overlay attn_bf+Abig (written at
                                                //   im2col, after all readers done)
    float* dots      = w + 10701440;            // 3,211,264 (dead after softmax)
    u16*   h2cb      = (u16*)(w + 11364992);    // bf16 [6272][256] -> ends 12,970,624
    u16*   hp        = (u16*)(w + 17123968);    // zero-padded h buffer -> ends 17,787,520
    float* G         = w + 17787520;            // [6272][64] fp32 -> ends 18,188,928
    u16*   wpad      = (u16*)(w + 18188928);    // [64][256] bf16 -> ends 18,197,120 (72.8MB)

    // merged prep: hp zero + ct1 wtrans + ct2 wpad + pooled zero
    prep_kernel<<<1256, 256, 0, stream>>>(hp, ct1_w, wt1bf, ct2_w, wpad, pooled);
    // fused norm + bf16 cvt (z -> Abig left half; protos -> protos_bf)
    norm_cvt_kernel<<<6272, 256, 0, stream>>>(z, Abig, 2048, zn);
    norm_cvt_kernel<<<512, 256, 0, stream>>>(protos, protos_bf, 1024, pn);
    transpose_cvt_kernel<<<dim3(16, 8), 256, 0, stream>>>(protos, protosT, 512, 1024);
    transpose_cvt_kernel<<<dim3(16, 32), 256, 0, stream>>>(gate_w, gwT, 2048, 1024);
    // dots = z @ protos^T (M=6272, N=512, K=1024), 64x128 tiles, XCD swizzle
    mfma_gemm_kernel<2, 4, 0, true><<<dim3(98, 4), 256, 0, stream>>>(
        Abig, 2048, 0, protos_bf, 1024, 0, 6272, 512, 1024,
        dots, nullptr, 0, nullptr, nullptr, nullptr, 0, nullptr);
    // softmax -> attn (fp32 out) + attn_bf
    softmax_kernel<<<6272, 256, 0, stream>>>(dots, zn, pn, attn, attn_bf);
    // z_hat = attn @ protos (M=6272, N=1024, K=512), 128x128 tiles (r11 best)
    mfma_gemm_kernel<4, 4, 1, true><<<dim3(49, 8), 256, 0, stream>>>(
        attn_bf, 512, 0, protosT, 512, 0, 6272, 1024, 512,
        nullptr, Abig + 1024, 2048, nullptr, nullptr, nullptr, 0, nullptr);
    // gate GEMM (K=2048) + sigmoid blend + fused pooling, 128x128 (r11 best)
    mfma_gemm_kernel<4, 4, 2, true><<<dim3(49, 8), 256, 0, stream>>>(
        Abig, 2048, 0, gwT, 2048, 0, 6272, 1024, 2048,
        nullptr, nullptr, 0, gate_b, Abig, Abig + 1024, 2048, pooled);
    // decoder: single MFMA GEMM, dec_w fp32 read once, writes hp directly
    dec_gemm_kernel<<<196, 256, 0, stream>>>(pooled, dec_w, dec_b, hp);
    // convT1 as grouped MFMA GEMM, 32x64 tiles -> 800 blocks
    im2col_kernel<<<6400, 256, 0, stream>>>(hp, A_cls);
    mfma_gemm_kernel<1, 2, 3, false><<<dim3(50, 4, 4), 256, 0, stream>>>(
        A_cls, 2048, (size_t)1600 * 2048, wt1bf, 2048, (size_t)256 * 2048,
        1600, 256, 2048, nullptr, h2cb, 0, ct1_b, nullptr, nullptr, 0, nullptr);
    // convT2 as GEMM (M=6272, N=64, K=256), 32x64 tiles -> 196 blocks
    mfma_gemm_kernel<1, 2, 0, false><<<dim3(196, 1), 256, 0, stream>>>(
        h2cb, 256, 0, wpad, 256, 0, 6272, 64, 256,
        G, nullptr, 0, nullptr, nullptr, nullptr, 0, nullptr);
    convt2_gather_kernel<<<294, 256, 0, stream>>>(G, ct2_b, xout);
}

// Round 15
// 186.257 us; speedup vs baseline: 1.1652x; 1.0180x over previous
//
#include <hip/hip_runtime.h>
#include <cstdint>
#include <cstddef>
#include <cmath>

#define EPS_COS 1e-8f

typedef unsigned short u16;
typedef __attribute__((ext_vector_type(8))) short short8v;
typedef __attribute__((ext_vector_type(4))) short short4v;
typedef __attribute__((ext_vector_type(4))) float f32x4;

__device__ __forceinline__ u16 f2bf(float x) {
    unsigned int u = __float_as_uint(x);
    return (u16)((u + 0x7FFFu + ((u >> 16) & 1u)) >> 16);  // RNE
}
__device__ __forceinline__ float bf2f(u16 h) {
    return __uint_as_float(((unsigned int)h) << 16);
}

// ---------------------------------------------------------------------------
// fused row L2 norm + bf16 convert (C fixed = 1024), one block per row
// ---------------------------------------------------------------------------
__global__ __launch_bounds__(256) void norm_cvt_kernel(const float* __restrict__ src,
                                                       u16* __restrict__ dst, int dstStride,
                                                       float* __restrict__ norms) {
    int r = blockIdx.x;
    int t = threadIdx.x;
    const float4 v = *reinterpret_cast<const float4*>(&src[(size_t)r * 1024 + t * 4]);
    short4v o;
    o[0] = f2bf(v.x); o[1] = f2bf(v.y); o[2] = f2bf(v.z); o[3] = f2bf(v.w);
    *reinterpret_cast<short4v*>(&dst[(size_t)r * dstStride + t * 4]) = o;
    float ss = v.x * v.x + v.y * v.y + v.z * v.z + v.w * v.w;
#pragma unroll
    for (int off = 32; off > 0; off >>= 1) ss += __shfl_down(ss, off);
    __shared__ float red[4];
    int wave = t >> 6, lane = t & 63;
    if (lane == 0) red[wave] = ss;
    __syncthreads();
    if (t == 0) norms[r] = sqrtf(red[0] + red[1] + red[2] + red[3]);
}

// ---------------------------------------------------------------------------
// transpose + cvt: src [R][C] f32 -> dst [C][R] bf16 (64x64 LDS tiles, +1 pad)
// ---------------------------------------------------------------------------
__global__ __launch_bounds__(256) void transpose_cvt_kernel(const float* __restrict__ src,
                                                            u16* __restrict__ dst,
                                                            int R, int C) {
    __shared__ float tile[64][65];
    int c0 = blockIdx.x * 64, r0 = blockIdx.y * 64;
    int t = threadIdx.x;
#pragma unroll
    for (int j = 0; j < 16; ++j) {
        int idx = j * 256 + t;
        int r = idx >> 6, c = idx & 63;
        tile[r][c] = src[(size_t)(r0 + r) * C + c0 + c];
    }
    __syncthreads();
#pragma unroll
    for (int j = 0; j < 16; ++j) {
        int idx = j * 256 + t;
        int c = idx >> 6, r = idx & 63;
        dst[(size_t)(c0 + c) * R + r0 + r] = f2bf(tile[r][c]);
    }
}

// ---------------------------------------------------------------------------
// merged prep: [0,165888) zero hp; [..+131072) ct1_w -> wt1bf;
// [..+16384) ct2_w -> wpad; [..+8192) zero pooled. 1256 blocks x 256.
// ---------------------------------------------------------------------------
__global__ __launch_bounds__(256) void prep_kernel(u16* __restrict__ hp,
                                                   const float* __restrict__ ct1w,
                                                   u16* __restrict__ wt,
                                                   const float* __restrict__ ct2w,
                                                   u16* __restrict__ wpad,
                                                   float* __restrict__ pooled) {
    int idx = blockIdx.x * 256 + threadIdx.x;
    if (idx < 165888) {
        short8v zv = {0, 0, 0, 0, 0, 0, 0, 0};
        *reinterpret_cast<short8v*>(hp + (size_t)idx * 8) = zv;
    } else if (idx < 165888 + 131072) {
        int i = idx - 165888;  // ic*256+oc
        int oc = i & 255, ic = i >> 8;
        float v[16];
#pragma unroll
        for (int j = 0; j < 16; ++j) v[j] = ct1w[(size_t)i * 16 + j];
#pragma unroll
        for (int pp = 0; pp < 4; ++pp) {
            int py = pp >> 1, px = pp & 1;
#pragma unroll
            for (int tap = 0; tap < 4; ++tap) {
                int ty = tap >> 1, tx = tap & 1;
                int ky = (1 - py) + 2 * ty;
                int kx = (1 - px) + 2 * tx;
                wt[((size_t)(pp * 256 + oc)) * 2048 + ic * 4 + tap] = f2bf(v[ky * 4 + kx]);
            }
        }
    } else if (idx < 165888 + 131072 + 16384) {
        int i = idx - 165888 - 131072;
        int ic = i & 255;
        int col = i >> 8;
        float v = 0.0f;
        if (col < 48) {
            int kx = col & 3, ky = (col >> 2) & 3, oc = col >> 4;
            v = ct2w[((size_t)ic * 3 + oc) * 16 + ky * 4 + kx];
        }
        wpad[i] = f2bf(v);
    } else {
        int i = idx - 165888 - 131072 - 16384;  // < 8192
        *reinterpret_cast<f32x4*>(pooled + (size_t)i * 4) = (f32x4){0.f, 0.f, 0.f, 0.f};
    }
}

// ---------------------------------------------------------------------------
// bf16 MFMA GEMM, all-NT, BK=64 reg-staged: C = A[M,K] * B[N,K]^T
// blockIdx.z selects (A,B) via zsA/zsB. BM=FM*32, BN=FN*32; 4 waves (2x2).
// LDS: [row][64 k] bf16; 16B chunk c stored at slot c^(row&7) (8-way XOR ->
// ds_read 2-way aliasing = free).
// SWZ: XCD remap with M-MAJOR decode (r15): hw-id chunk per XCD decodes to
// ~nwg/8/gy consecutive M-tiles x ALL N-strips, so the per-XCD A-panel chunk
// (the big operand) fits the 4MB L2 and is fetched ~once; only small B
// replicates across XCDs. (r8-r14 decode was N-strip-major: every XCD
// re-streamed full A -> gate FETCH 144-205MB.) Requires nwg%8==0.
// EPI 0: fp32 store Cf[M][N]
// EPI 1: bf16 store Cb[row*sCb+col]
// EPI 2: g=sigmoid(acc+bias[col]); fused = g*z + (1-g)*z_hat (BOTH bf16 from
//        zbf/zhbf, stride szh); atomicAdd per-(batch,col) into outf (pooled)
// EPI 3: relu(acc+bias[col]) -> bf16 Cb[((b*4+z)*49+s)*256+col], row<1568
// ---------------------------------------------------------------------------
template <int FM, int FN, int EPI, bool SWZ>
__global__ __launch_bounds__(256) void mfma_gemm_kernel(
    const u16* __restrict__ A, int sA, size_t zsA,
    const u16* __restrict__ B, int sB, size_t zsB,
    int M, int N, int K,
    float* __restrict__ Cf,
    u16* __restrict__ Cb, int sCb,
    const float* __restrict__ bias,
    const u16* __restrict__ zbf,
    const u16* __restrict__ zhbf, int szh,
    float* __restrict__ outf) {
    constexpr int BM = FM * 32, BN = FN * 32;
    constexpr int NA = BM / 32;  // short8 chunks per thread (A), BK=64
    constexpr int NB = BN / 32;
    __shared__ __align__(16) u16 As[BM * 64];
    __shared__ __align__(16) u16 Bs[BN * 64];
    int bx = blockIdx.x, by = blockIdx.y;
    if (SWZ) {
        int gx = gridDim.x, gy = gridDim.y;
        int nwg = gx * gy;
        int lb = by * gx + bx;                     // hardware dispatch id
        int flat = (lb & 7) * (nwg >> 3) + (lb >> 3);  // XCD k owns one contiguous chunk
        bx = flat / gy;                            // M-major decode: chunk = few
        by = flat % gy;                            //   M-tiles x ALL N-strips
    }
    A += (size_t)blockIdx.z * zsA;
    B += (size_t)blockIdx.z * zsB;
    const int t = threadIdx.x;
    const int lane = t & 63;
    const int wid = t >> 6;
    const int wm = wid >> 1, wn = wid & 1;
    const int m0 = bx * BM, n0 = by * BN;
    const int g = lane >> 4, lr = lane & 15;

    f32x4 acc[FM][FN];
#pragma unroll
    for (int i = 0; i < FM; ++i)
#pragma unroll
        for (int j = 0; j < FN; ++j) acc[i][j] = (f32x4){0.f, 0.f, 0.f, 0.f};

    short8v ra[NA], rb[NB];
#pragma unroll
    for (int j = 0; j < NA; ++j) {
        int c = j * 256 + t, row = c >> 3, ck = c & 7;
        ra[j] = *reinterpret_cast<const short8v*>(A + (size_t)(m0 + row) * sA + ck * 8);
    }
#pragma unroll
    for (int j = 0; j < NB; ++j) {
        int c = j * 256 + t, row = c >> 3, ck = c & 7;
        rb[j] = *reinterpret_cast<const short8v*>(B + (size_t)(n0 + row) * sB + ck * 8);
    }

    for (int k0 = 0; k0 < K; k0 += 64) {
        __syncthreads();
#pragma unroll
        for (int j = 0; j < NA; ++j) {
            int c = j * 256 + t, row = c >> 3, ck = c & 7;
            *reinterpret_cast<short8v*>(As + row * 64 + ((ck ^ (row & 7)) << 3)) = ra[j];
        }
#pragma unroll
        for (int j = 0; j < NB; ++j) {
            int c = j * 256 + t, row = c >> 3, ck = c & 7;
            *reinterpret_cast<short8v*>(Bs + row * 64 + ((ck ^ (row & 7)) << 3)) = rb[j];
        }
        __syncthreads();
        if (k0 + 64 < K) {  // prefetch next tile into regs, overlaps MFMA below
#pragma unroll
            for (int j = 0; j < NA; ++j) {
                int c = j * 256 + t, row = c >> 3, ck = c & 7;
                ra[j] = *reinterpret_cast<const short8v*>(A + (size_t)(m0 + row) * sA + k0 + 64 + ck * 8);
            }
#pragma unroll
            for (int j = 0; j < NB; ++j) {
                int c = j * 256 + t, row = c >> 3, ck = c & 7;
                rb[j] = *reinterpret_cast<const short8v*>(B + (size_t)(n0 + row) * sB + k0 + 64 + ck * 8);
            }
        }
#pragma unroll
        for (int kk = 0; kk < 2; ++kk) {
            short8v af[FM], bfr[FN];
#pragma unroll
            for (int fm = 0; fm < FM; ++fm) {
                int row = wm * (FM * 16) + fm * 16 + lr;
                int rc = (kk * 4 + g) ^ (row & 7);
                af[fm] = *reinterpret_cast<const short8v*>(As + row * 64 + rc * 8);
            }
#pragma unroll
            for (int fn = 0; fn < FN; ++fn) {
                int col = wn * (FN * 16) + fn * 16 + lr;
                int rc = (kk * 4 + g) ^ (col & 7);
                bfr[fn] = *reinterpret_cast<const short8v*>(Bs + col * 64 + rc * 8);
            }
#pragma unroll
            for (int fm = 0; fm < FM; ++fm)
#pragma unroll
                for (int fn = 0; fn < FN; ++fn)
                    acc[fm][fn] = __builtin_amdgcn_mfma_f32_16x16x32_bf16(
                        af[fm], bfr[fn], acc[fm][fn], 0, 0, 0);
        }
    }

    if (EPI == 2) {
        // gate + blend (both operands bf16, resident rows of Abig) + pool
#pragma unroll
        for (int fn = 0; fn < FN; ++fn) {
            int col = n0 + wn * (FN * 16) + fn * 16 + lr;
            int base = m0 + wm * (FM * 16) + g * 4;
            int b0 = base / 196;
            float p0 = 0.f, p1 = 0.f;
#pragma unroll
            for (int fm = 0; fm < FM; ++fm) {
#pragma unroll
                for (int r = 0; r < 4; ++r) {
                    int row = base + fm * 16 + r;
                    float v = acc[fm][fn][r];
                    float gs = 1.0f / (1.0f + __expf(-(v + bias[col])));
                    float zv = bf2f(zbf[(size_t)row * szh + col]);
                    float zh = bf2f(zhbf[(size_t)row * szh + col]);
                    float fused = gs * zv + (1.0f - gs) * zh;
                    bool same = (row / 196) == b0;
                    p0 += same ? fused : 0.f;
                    p1 += same ? 0.f : fused;
                }
            }
            atomicAdd(&outf[(size_t)b0 * 1024 + col], p0);
            if (p1 != 0.f) atomicAdd(&outf[(size_t)(b0 + 1) * 1024 + col], p1);
        }
    } else {
#pragma unroll
        for (int fm = 0; fm < FM; ++fm) {
#pragma unroll
            for (int fn = 0; fn < FN; ++fn) {
#pragma unroll
                for (int r = 0; r < 4; ++r) {
                    int row = m0 + wm * (FM * 16) + fm * 16 + g * 4 + r;
                    int col = n0 + wn * (FN * 16) + fn * 16 + lr;
                    float v = acc[fm][fn][r];
                    if (EPI == 0) {
                        Cf[(size_t)row * N + col] = v;
                    } else if (EPI == 1) {
                        Cb[(size_t)row * sCb + col] = f2bf(v);
                    } else {  // EPI == 3
                        if (row < 1568) {
                            float vv = fmaxf(v + bias[col], 0.0f);
                            int bb = row / 49, ss = row - bb * 49;
                            Cb[(((size_t)bb * 4 + blockIdx.z) * 49 + ss) * 256 + col] = f2bf(vv);
                        }
                    }
                }
            }
        }
    }
}

// ---------------------------------------------------------------------------
// decoder as one MFMA GEMM, B staged NN directly from fp32 dec_w (read ONCE):
// h[b][c] = (pooled[b][:]/196) @ dec_w[:,c] + dec_b[c] -> bf16 hp interior.
// M=32, BN=128, BK=64, grid (196). LDS row stride 72 u16.
// ---------------------------------------------------------------------------
__global__ __launch_bounds__(256) void dec_gemm_kernel(const float* __restrict__ pooled,
                                                       const float* __restrict__ dec_w,
                                                       const float* __restrict__ dec_b,
                                                       u16* __restrict__ hp) {
    __shared__ __align__(16) u16 As[32 * 72];
    __shared__ __align__(16) u16 Bs[128 * 72];
    const int t = threadIdx.x;
    const int lane = t & 63;
    const int wid = t >> 6;
    const int wm = wid >> 1, wn = wid & 1;
    const int n0 = blockIdx.x * 128;
    const int g = lane >> 4, lr = lane & 15;

    const int ar = t >> 3;
    const int ak = (t & 7) * 8;
    const int bn4 = (t & 31) * 4;
    const int bk4 = (t >> 5) * 4;
    const int bswz = ((bn4 >> 2) & 3) << 3;
    const int bkp = (bk4 ^ bswz);

    f32x4 acc[4];
#pragma unroll
    for (int j = 0; j < 4; ++j) acc[j] = (f32x4){0.f, 0.f, 0.f, 0.f};

    f32x4 ra[2];
    f32x4 rb[2][4];
#pragma unroll
    for (int h = 0; h < 2; ++h)
        ra[h] = *reinterpret_cast<const f32x4*>(pooled + ar * 1024 + ak + h * 4);
#pragma unroll
    for (int q = 0; q < 2; ++q)
#pragma unroll
        for (int i = 0; i < 4; ++i)
            rb[q][i] = *reinterpret_cast<const f32x4*>(
                dec_w + (size_t)(bk4 + q * 32 + i) * 25088 + n0 + bn4);

    for (int k0 = 0; k0 < 1024; k0 += 64) {
        __syncthreads();
        {
            short8v o;
#pragma unroll
            for (int h = 0; h < 2; ++h) {
                o[h * 4 + 0] = f2bf(ra[h].x * (1.0f / 196.0f));
                o[h * 4 + 1] = f2bf(ra[h].y * (1.0f / 196.0f));
                o[h * 4 + 2] = f2bf(ra[h].z * (1.0f / 196.0f));
                o[h * 4 + 3] = f2bf(ra[h].w * (1.0f / 196.0f));
            }
            *reinterpret_cast<short8v*>(As + ar * 72 + ak) = o;
        }
#pragma unroll
        for (int q = 0; q < 2; ++q) {
#pragma unroll
            for (int j = 0; j < 4; ++j) {
                short4v o4;
                o4[0] = f2bf(rb[q][0][j]);
                o4[1] = f2bf(rb[q][1][j]);
                o4[2] = f2bf(rb[q][2][j]);
                o4[3] = f2bf(rb[q][3][j]);
                *reinterpret_cast<short4v*>(Bs + (bn4 + j) * 72 + bkp + q * 32) = o4;
            }
        }
        __syncthreads();
        if (k0 + 64 < 1024) {
#pragma unroll
            for (int h = 0; h < 2; ++h)
                ra[h] = *reinterpret_cast<const f32x4*>(
                    pooled + ar * 1024 + k0 + 64 + ak + h * 4);
#pragma unroll
            for (int q = 0; q < 2; ++q)
#pragma unroll
                for (int i = 0; i < 4; ++i)
                    rb[q][i] = *reinterpret_cast<const f32x4*>(
                        dec_w + (size_t)(k0 + 64 + bk4 + q * 32 + i) * 25088 + n0 + bn4);
        }
#pragma unroll
        for (int kk = 0; kk < 2; ++kk) {
            int row = wm * 16 + lr;
            short8v af = *reinterpret_cast<const short8v*>(As + row * 72 + kk * 32 + g * 8);
#pragma unroll
            for (int fn = 0; fn < 4; ++fn) {
                int col = wn * 64 + fn * 16 + lr;
                int ch = (kk * 32 + g * 8) ^ (((col >> 2) & 3) << 3);
                short8v bf8 = *reinterpret_cast<const short8v*>(Bs + col * 72 + ch);
                acc[fn] = __builtin_amdgcn_mfma_f32_16x16x32_bf16(af, bf8, acc[fn], 0, 0, 0);
            }
        }
    }
#pragma unroll
    for (int fn = 0; fn < 4; ++fn) {
#pragma unroll
        for (int r = 0; r < 4; ++r) {
            int row = wm * 16 + g * 4 + r;
            int col = n0 + wn * 64 + fn * 16 + lr;
            float v = acc[fn][r] + dec_b[col];
            int ic = col / 49, sp = col - ic * 49;
            int sy = sp / 7, sx = sp - sy * 7;
            hp[((size_t)row * 512 + ic) * 81 + (sy + 1) * 9 + sx + 1] = f2bf(v);
        }
    }
}

// ---------------------------------------------------------------------------
// softmax over K=512 with cosine scaling; writes attn (fp32, d_out) + bf16 copy
// ---------------------------------------------------------------------------
__global__ __launch_bounds__(256) void softmax_kernel(const float* __restrict__ dots,
                                                      const float* __restrict__ zn,
                                                      const float* __restrict__ pn,
                                                      float* __restrict__ attn,
                                                      u16* __restrict__ attn_bf) {
    int m = blockIdx.x;
    int t = threadIdx.x;
    float zm = zn[m];
    float d0 = dots[(size_t)m * 512 + t];
    float d1 = dots[(size_t)m * 512 + t + 256];
    float v0 = d0 / fmaxf(zm * pn[t], EPS_COS);
    float v1 = d1 / fmaxf(zm * pn[t + 256], EPS_COS);
    float mx = fmaxf(v0, v1);
#pragma unroll
    for (int off = 32; off > 0; off >>= 1) mx = fmaxf(mx, __shfl_down(mx, off));
    __shared__ float red[8];
    int wave = t >> 6, lane = t & 63;
    if (lane == 0) red[wave] = mx;
    __syncthreads();
    if (t == 0) red[4] = fmaxf(fmaxf(red[0], red[1]), fmaxf(red[2], red[3]));
    __syncthreads();
    mx = red[4];
    float e0 = expf(v0 - mx), e1 = expf(v1 - mx);
    float s = e0 + e1;
#pragma unroll
    for (int off = 32; off > 0; off >>= 1) s += __shfl_down(s, off);
    if (lane == 0) red[wave] = s;
    __syncthreads();
    if (t == 0) red[5] = 1.0f / (red[0] + red[1] + red[2] + red[3]);
    __syncthreads();
    float r = red[5];
    float a0 = e0 * r, a1 = e1 * r;
    attn[(size_t)m * 512 + t] = a0;
    attn[(size_t)m * 512 + t + 256] = a1;
    attn_bf[(size_t)m * 512 + t] = f2bf(a0);
    attn_bf[(size_t)m * 512 + t + 256] = f2bf(a1);
}

// ---------------------------------------------------------------------------
// im2col for convT1 parity classes: A[p][row=b*49+s][k=ic*4+tap] bf16
// ---------------------------------------------------------------------------
__global__ __launch_bounds__(256) void im2col_kernel(const u16* __restrict__ hp,
                                                     u16* __restrict__ A) {
    int idx = blockIdx.x * 256 + threadIdx.x;  // < 1,638,400
    int k8 = idx & 255;                        // 8 cols = 2 ic x 4 taps
    int pr = idx >> 8;
    int p = pr / 1600;
    int row = pr - p * 1600;
    short8v o = {0, 0, 0, 0, 0, 0, 0, 0};
    if (row < 1568) {
        int b = row / 49, s = row - b * 49;
        int sy = s / 7, sx = s - sy * 7;
        int r0 = sy + (p >> 1) + 1;
        int c0 = sx + (p & 1) + 1;
        int ic0 = k8 * 2;
        const u16* hb = hp + ((size_t)b * 512 + ic0) * 81;
#pragma unroll
        for (int j = 0; j < 2; ++j) {
            o[j * 4 + 0] = hb[r0 * 9 + c0];
            o[j * 4 + 1] = hb[r0 * 9 + c0 - 1];
            o[j * 4 + 2] = hb[(r0 - 1) * 9 + c0];
            o[j * 4 + 3] = hb[(r0 - 1) * 9 + c0 - 1];
            hb += 81;
        }
    }
    *reinterpret_cast<short8v*>(A + (size_t)idx * 8) = o;
}

// ---------------------------------------------------------------------------
// convT2 gather: out[o] = bias[oc] + sum_{<=4 taps} G[row][oc*16+ky*4+kx]
// ---------------------------------------------------------------------------
__global__ __launch_bounds__(256) void convt2_gather_kernel(const float* __restrict__ G,
                                                            const float* __restrict__ bias,
                                                            float* __restrict__ out) {
    int o = blockIdx.x * 256 + threadIdx.x;  // < 75264
    int ox = o % 28;
    int oy = (o / 28) % 28;
    int oc = (o / 784) % 3;
    int b = o / 2352;
    int by = (oy + 1) >> 1, bx = (ox + 1) >> 1;
    float acc = bias[oc];
#pragma unroll
    for (int ty = 0; ty < 2; ++ty) {
        int iy = by - ty;
        if ((unsigned)iy >= 14u) continue;
#pragma unroll
        for (int tx = 0; tx < 2; ++tx) {
            int ix = bx - tx;
            if ((unsigned)ix >= 14u) continue;
            int p = (iy & 1) * 2 + (ix & 1);
            int row = ((b * 4 + p) * 49) + (iy >> 1) * 7 + (ix >> 1);
            int ky = oy + 1 - 2 * iy, kx = ox + 1 - 2 * ix;
            acc += G[(size_t)row * 64 + oc * 16 + ky * 4 + kx];
        }
    }
    out[o] = acc;
}

// ---------------------------------------------------------------------------
extern "C" void kernel_launch(void* const* d_in, const int* in_sizes, int n_in,
                              void* d_out, int out_size, void* d_ws, size_t ws_size,
                              hipStream_t stream) {
    const float* z      = (const float*)d_in[0];  // [32,196,1024]
    const float* protos = (const float*)d_in[1];  // [512,1024]
    const float* gate_w = (const float*)d_in[2];  // [2048,1024]
    const float* gate_b = (const float*)d_in[3];  // [1024]
    const float* dec_w  = (const float*)d_in[4];  // [1024,25088]
    const float* dec_b  = (const float*)d_in[5];  // [25088]
    const float* ct1_w  = (const float*)d_in[6];  // [512,256,4,4]
    const float* ct1_b  = (const float*)d_in[7];  // [256]
    const float* ct2_w  = (const float*)d_in[8];  // [256,3,4,4]
    const float* ct2_b  = (const float*)d_in[9];  // [3]

    float* xout = (float*)d_out;   // x_recon 75264
    float* attn = xout + 75264;    // attn 3211264

    float* w = (float*)d_ws;
    float* pn        = w;                       // 512
    float* zn        = w + 512;                 // 6272
    float* pooled    = w + 6784;                // 32768 (atomic-accumulated token sums)
    u16*   wt1bf     = (u16*)(w + 51840);       // 2,097,152 u16 -> ends 1,100,416
    u16*   protos_bf = (u16*)(w + 1100416);     // 524288 u16
    u16*   protosT   = (u16*)(w + 1362560);     // 524288 u16
    u16*   gwT       = (u16*)(w + 1624704);     // 2,097,152 u16 -> ends 2,673,280
    u16*   attn_bf   = (u16*)(w + 2673280);     // 3,211,264 u16 -> ends 4,278,912
    u16*   Abig      = (u16*)(w + 4278912);     // [6272][2048] u16 -> ends 10,701,440
    u16*   A_cls     = (u16*)(w + 2673280);     // [4][1600][2048] u16 -> ends 9,226,880;
                                                //   overlay attn_bf+Abig (written at
                                                //   im2col, after all readers done)
    float* dots      = w + 10701440;            // 3,211,264 (dead after softmax)
    u16*   h2cb      = (u16*)(w + 11364992);    // bf16 [6272][256] -> ends 12,970,624
    u16*   hp        = (u16*)(w + 17123968);    // zero-padded h buffer -> ends 17,787,520
    float* G         = w + 17787520;            // [6272][64] fp32 -> ends 18,188,928
    u16*   wpad      = (u16*)(w + 18188928);    // [64][256] bf16 -> ends 18,197,120 (72.8MB)

    // merged prep: hp zero + ct1 wtrans + ct2 wpad + pooled zero
    prep_kernel<<<1256, 256, 0, stream>>>(hp, ct1_w, wt1bf, ct2_w, wpad, pooled);
    // fused norm + bf16 cvt (z -> Abig left half; protos -> protos_bf)
    norm_cvt_kernel<<<6272, 256, 0, stream>>>(z, Abig, 2048, zn);
    norm_cvt_kernel<<<512, 256, 0, stream>>>(protos, protos_bf, 1024, pn);
    transpose_cvt_kernel<<<dim3(16, 8), 256, 0, stream>>>(protos, protosT, 512, 1024);
    transpose_cvt_kernel<<<dim3(16, 32), 256, 0, stream>>>(gate_w, gwT, 2048, 1024);
    // dots = z @ protos^T (M=6272, N=512, K=1024), 64x128, M-major XCD swizzle
    mfma_gemm_kernel<2, 4, 0, true><<<dim3(98, 4), 256, 0, stream>>>(
        Abig, 2048, 0, protos_bf, 1024, 0, 6272, 512, 1024,
        dots, nullptr, 0, nullptr, nullptr, nullptr, 0, nullptr);
    // softmax -> attn (fp32 out) + attn_bf
    softmax_kernel<<<6272, 256, 0, stream>>>(dots, zn, pn, attn, attn_bf);
    // z_hat = attn @ protos (M=6272, N=1024, K=512), 128x128, M-major swizzle
    mfma_gemm_kernel<4, 4, 1, true><<<dim3(49, 8), 256, 0, stream>>>(
        attn_bf, 512, 0, protosT, 512, 0, 6272, 1024, 512,
        nullptr, Abig + 1024, 2048, nullptr, nullptr, nullptr, 0, nullptr);
    // gate GEMM (K=2048) + sigmoid blend + fused pooling, 128x128, M-major swz
    mfma_gemm_kernel<4, 4, 2, true><<<dim3(49, 8), 256, 0, stream>>>(
        Abig, 2048, 0, gwT, 2048, 0, 6272, 1024, 2048,
        nullptr, nullptr, 0, gate_b, Abig, Abig + 1024, 2048, pooled);
    // decoder: single MFMA GEMM, dec_w fp32 read once, writes hp directly
    dec_gemm_kernel<<<196, 256, 0, stream>>>(pooled, dec_w, dec_b, hp);
    // convT1 as grouped MFMA GEMM, 32x64 tiles -> 800 blocks
    im2col_kernel<<<6400, 256, 0, stream>>>(hp, A_cls);
    mfma_gemm_kernel<1, 2, 3, false><<<dim3(50, 4, 4), 256, 0, stream>>>(
        A_cls, 2048, (size_t)1600 * 2048, wt1bf, 2048, (size_t)256 * 2048,
        1600, 256, 2048, nullptr, h2cb, 0, ct1_b, nullptr, nullptr, 0, nullptr);
    // convT2 as GEMM (M=6272, N=64, K=256), 32x64 tiles -> 196 blocks
    mfma_gemm_kernel<1, 2, 0, false><<<dim3(196, 1), 256, 0, stream>>>(
        h2cb, 256, 0, wpad, 256, 0, 6272, 64, 256,
        G, nullptr, 0, nullptr, nullptr, nullptr, 0, nullptr);
    convt2_gather_kernel<<<294, 256, 0, stream>>>(G, ct2_b, xout);
}

// Round 16
// 184.195 us; speedup vs baseline: 1.1782x; 1.0112x over previous
//
#include <hip/hip_runtime.h>
#include <cstdint>
#include <cstddef>
#include <cmath>

#define EPS_COS 1e-8f

typedef unsigned short u16;
typedef __attribute__((ext_vector_type(8))) short short8v;
typedef __attribute__((ext_vector_type(4))) short short4v;
typedef __attribute__((ext_vector_type(4))) float f32x4;

__device__ __forceinline__ u16 f2bf(float x) {
    unsigned int u = __float_as_uint(x);
    return (u16)((u + 0x7FFFu + ((u >> 16) & 1u)) >> 16);  // RNE
}
__device__ __forceinline__ float bf2f(u16 h) {
    return __uint_as_float(((unsigned int)h) << 16);
}

// ---------------------------------------------------------------------------
// fused row L2 norm + bf16 convert (C fixed = 1024), one block per row
// ---------------------------------------------------------------------------
__global__ __launch_bounds__(256) void norm_cvt_kernel(const float* __restrict__ src,
                                                       u16* __restrict__ dst, int dstStride,
                                                       float* __restrict__ norms) {
    int r = blockIdx.x;
    int t = threadIdx.x;
    const float4 v = *reinterpret_cast<const float4*>(&src[(size_t)r * 1024 + t * 4]);
    short4v o;
    o[0] = f2bf(v.x); o[1] = f2bf(v.y); o[2] = f2bf(v.z); o[3] = f2bf(v.w);
    *reinterpret_cast<short4v*>(&dst[(size_t)r * dstStride + t * 4]) = o;
    float ss = v.x * v.x + v.y * v.y + v.z * v.z + v.w * v.w;
#pragma unroll
    for (int off = 32; off > 0; off >>= 1) ss += __shfl_down(ss, off);
    __shared__ float red[4];
    int wave = t >> 6, lane = t & 63;
    if (lane == 0) red[wave] = ss;
    __syncthreads();
    if (t == 0) norms[r] = sqrtf(red[0] + red[1] + red[2] + red[3]);
}

// ---------------------------------------------------------------------------
// transpose + cvt: src [R][C] f32 -> dst [C][R] bf16 (64x64 LDS tiles, +1 pad)
// ---------------------------------------------------------------------------
__global__ __launch_bounds__(256) void transpose_cvt_kernel(const float* __restrict__ src,
                                                            u16* __restrict__ dst,
                                                            int R, int C) {
    __shared__ float tile[64][65];
    int c0 = blockIdx.x * 64, r0 = blockIdx.y * 64;
    int t = threadIdx.x;
#pragma unroll
    for (int j = 0; j < 16; ++j) {
        int idx = j * 256 + t;
        int r = idx >> 6, c = idx & 63;
        tile[r][c] = src[(size_t)(r0 + r) * C + c0 + c];
    }
    __syncthreads();
#pragma unroll
    for (int j = 0; j < 16; ++j) {
        int idx = j * 256 + t;
        int c = idx >> 6, r = idx & 63;
        dst[(size_t)(c0 + c) * R + r0 + r] = f2bf(tile[r][c]);
    }
}

// ---------------------------------------------------------------------------
// merged prep: [0,165888) zero hp; [..+131072) ct1_w -> wt1bf;
// [..+16384) ct2_w -> wpad; [..+8192) zero pooled. 1256 blocks x 256.
// ---------------------------------------------------------------------------
__global__ __launch_bounds__(256) void prep_kernel(u16* __restrict__ hp,
                                                   const float* __restrict__ ct1w,
                                                   u16* __restrict__ wt,
                                                   const float* __restrict__ ct2w,
                                                   u16* __restrict__ wpad,
                                                   float* __restrict__ pooled) {
    int idx = blockIdx.x * 256 + threadIdx.x;
    if (idx < 165888) {
        short8v zv = {0, 0, 0, 0, 0, 0, 0, 0};
        *reinterpret_cast<short8v*>(hp + (size_t)idx * 8) = zv;
    } else if (idx < 165888 + 131072) {
        int i = idx - 165888;  // ic*256+oc
        int oc = i & 255, ic = i >> 8;
        float v[16];
#pragma unroll
        for (int j = 0; j < 16; ++j) v[j] = ct1w[(size_t)i * 16 + j];
#pragma unroll
        for (int pp = 0; pp < 4; ++pp) {
            int py = pp >> 1, px = pp & 1;
#pragma unroll
            for (int tap = 0; tap < 4; ++tap) {
                int ty = tap >> 1, tx = tap & 1;
                int ky = (1 - py) + 2 * ty;
                int kx = (1 - px) + 2 * tx;
                wt[((size_t)(pp * 256 + oc)) * 2048 + ic * 4 + tap] = f2bf(v[ky * 4 + kx]);
            }
        }
    } else if (idx < 165888 + 131072 + 16384) {
        int i = idx - 165888 - 131072;
        int ic = i & 255;
        int col = i >> 8;
        float v = 0.0f;
        if (col < 48) {
            int kx = col & 3, ky = (col >> 2) & 3, oc = col >> 4;
            v = ct2w[((size_t)ic * 3 + oc) * 16 + ky * 4 + kx];
        }
        wpad[i] = f2bf(v);
    } else {
        int i = idx - 165888 - 131072 - 16384;  // < 8192
        *reinterpret_cast<f32x4*>(pooled + (size_t)i * 4) = (f32x4){0.f, 0.f, 0.f, 0.f};
    }
}

// ---------------------------------------------------------------------------
// bf16 MFMA GEMM, all-NT, BK=64 reg-staged: C = A[M,K] * B[N,K]^T
// Wave grid parameterized (r16): WM x WN waves, block = WM*WN*64 threads,
// BM = WM*FM*16, BN = WN*FN*16. Same 128x128 tiles with 8 waves (512 thr)
// doubles waves/CU for barrier-drain hiding WITHOUT changing traffic
// (r10/r12: tile shrink = refetch regression; this keeps tiles).
// LDS: [row][64 k] bf16; 16B chunk c stored at slot c^(row&7).
// SWZ: XCD remap, M-major decode (r15). Requires nwg%8==0.
// EPI 0/1/2/3 as before.
// ---------------------------------------------------------------------------
template <int FM, int FN, int WM, int WN, int EPI, bool SWZ>
__global__ __launch_bounds__(WM * WN * 64) void mfma_gemm_kernel(
    const u16* __restrict__ A, int sA, size_t zsA,
    const u16* __restrict__ B, int sB, size_t zsB,
    int M, int N, int K,
    float* __restrict__ Cf,
    u16* __restrict__ Cb, int sCb,
    const float* __restrict__ bias,
    const u16* __restrict__ zbf,
    const u16* __restrict__ zhbf, int szh,
    float* __restrict__ outf) {
    constexpr int NT = WM * WN * 64;
    constexpr int BM = WM * FM * 16, BN = WN * FN * 16;
    constexpr int NA = (BM * 8) / NT;  // short8 chunks per thread (A), BK=64
    constexpr int NB = (BN * 8) / NT;
    __shared__ __align__(16) u16 As[BM * 64];
    __shared__ __align__(16) u16 Bs[BN * 64];
    int bx = blockIdx.x, by = blockIdx.y;
    if (SWZ) {
        int gx = gridDim.x, gy = gridDim.y;
        int nwg = gx * gy;
        int lb = by * gx + bx;
        int flat = (lb & 7) * (nwg >> 3) + (lb >> 3);
        bx = flat / gy;   // M-major decode
        by = flat % gy;
    }
    A += (size_t)blockIdx.z * zsA;
    B += (size_t)blockIdx.z * zsB;
    const int t = threadIdx.x;
    const int lane = t & 63;
    const int wid = t >> 6;
    const int wm = wid / WN, wn = wid % WN;
    const int m0 = bx * BM, n0 = by * BN;
    const int g = lane >> 4, lr = lane & 15;

    f32x4 acc[FM][FN];
#pragma unroll
    for (int i = 0; i < FM; ++i)
#pragma unroll
        for (int j = 0; j < FN; ++j) acc[i][j] = (f32x4){0.f, 0.f, 0.f, 0.f};

    short8v ra[NA], rb[NB];
#pragma unroll
    for (int j = 0; j < NA; ++j) {
        int c = j * NT + t, row = c >> 3, ck = c & 7;
        ra[j] = *reinterpret_cast<const short8v*>(A + (size_t)(m0 + row) * sA + ck * 8);
    }
#pragma unroll
    for (int j = 0; j < NB; ++j) {
        int c = j * NT + t, row = c >> 3, ck = c & 7;
        rb[j] = *reinterpret_cast<const short8v*>(B + (size_t)(n0 + row) * sB + ck * 8);
    }

    for (int k0 = 0; k0 < K; k0 += 64) {
        __syncthreads();
#pragma unroll
        for (int j = 0; j < NA; ++j) {
            int c = j * NT + t, row = c >> 3, ck = c & 7;
            *reinterpret_cast<short8v*>(As + row * 64 + ((ck ^ (row & 7)) << 3)) = ra[j];
        }
#pragma unroll
        for (int j = 0; j < NB; ++j) {
            int c = j * NT + t, row = c >> 3, ck = c & 7;
            *reinterpret_cast<short8v*>(Bs + row * 64 + ((ck ^ (row & 7)) << 3)) = rb[j];
        }
        __syncthreads();
        if (k0 + 64 < K) {  // prefetch next tile into regs, overlaps MFMA below
#pragma unroll
            for (int j = 0; j < NA; ++j) {
                int c = j * NT + t, row = c >> 3, ck = c & 7;
                ra[j] = *reinterpret_cast<const short8v*>(A + (size_t)(m0 + row) * sA + k0 + 64 + ck * 8);
            }
#pragma unroll
            for (int j = 0; j < NB; ++j) {
                int c = j * NT + t, row = c >> 3, ck = c & 7;
                rb[j] = *reinterpret_cast<const short8v*>(B + (size_t)(n0 + row) * sB + k0 + 64 + ck * 8);
            }
        }
#pragma unroll
        for (int kk = 0; kk < 2; ++kk) {
            short8v af[FM], bfr[FN];
#pragma unroll
            for (int fm = 0; fm < FM; ++fm) {
                int row = wm * (FM * 16) + fm * 16 + lr;
                int rc = (kk * 4 + g) ^ (row & 7);
                af[fm] = *reinterpret_cast<const short8v*>(As + row * 64 + rc * 8);
            }
#pragma unroll
            for (int fn = 0; fn < FN; ++fn) {
                int col = wn * (FN * 16) + fn * 16 + lr;
                int rc = (kk * 4 + g) ^ (col & 7);
                bfr[fn] = *reinterpret_cast<const short8v*>(Bs + col * 64 + rc * 8);
            }
#pragma unroll
            for (int fm = 0; fm < FM; ++fm)
#pragma unroll
                for (int fn = 0; fn < FN; ++fn)
                    acc[fm][fn] = __builtin_amdgcn_mfma_f32_16x16x32_bf16(
                        af[fm], bfr[fn], acc[fm][fn], 0, 0, 0);
        }
    }

    if (EPI == 2) {
        // gate + blend (both operands bf16, resident rows of Abig) + pool
#pragma unroll
        for (int fn = 0; fn < FN; ++fn) {
            int col = n0 + wn * (FN * 16) + fn * 16 + lr;
            int base = m0 + wm * (FM * 16) + g * 4;
            int b0 = base / 196;
            float p0 = 0.f, p1 = 0.f;
#pragma unroll
            for (int fm = 0; fm < FM; ++fm) {
#pragma unroll
                for (int r = 0; r < 4; ++r) {
                    int row = base + fm * 16 + r;
                    float v = acc[fm][fn][r];
                    float gs = 1.0f / (1.0f + __expf(-(v + bias[col])));
                    float zv = bf2f(zbf[(size_t)row * szh + col]);
                    float zh = bf2f(zhbf[(size_t)row * szh + col]);
                    float fused = gs * zv + (1.0f - gs) * zh;
                    bool same = (row / 196) == b0;
                    p0 += same ? fused : 0.f;
                    p1 += same ? 0.f : fused;
                }
            }
            atomicAdd(&outf[(size_t)b0 * 1024 + col], p0);
            if (p1 != 0.f) atomicAdd(&outf[(size_t)(b0 + 1) * 1024 + col], p1);
        }
    } else {
#pragma unroll
        for (int fm = 0; fm < FM; ++fm) {
#pragma unroll
            for (int fn = 0; fn < FN; ++fn) {
#pragma unroll
                for (int r = 0; r < 4; ++r) {
                    int row = m0 + wm * (FM * 16) + fm * 16 + g * 4 + r;
                    int col = n0 + wn * (FN * 16) + fn * 16 + lr;
                    float v = acc[fm][fn][r];
                    if (EPI == 0) {
                        Cf[(size_t)row * N + col] = v;
                    } else if (EPI == 1) {
                        Cb[(size_t)row * sCb + col] = f2bf(v);
                    } else {  // EPI == 3
                        if (row < 1568) {
                            float vv = fmaxf(v + bias[col], 0.0f);
                            int bb = row / 49, ss = row - bb * 49;
                            Cb[(((size_t)bb * 4 + blockIdx.z) * 49 + ss) * 256 + col] = f2bf(vv);
                        }
                    }
                }
            }
        }
    }
}

// ---------------------------------------------------------------------------
// decoder as one MFMA GEMM, B staged NN directly from fp32 dec_w (read ONCE):
// h[b][c] = (pooled[b][:]/196) @ dec_w[:,c] + dec_b[c] -> bf16 hp interior.
// M=32, BN=128, BK=64, grid (196). LDS row stride 72 u16.
// ---------------------------------------------------------------------------
__global__ __launch_bounds__(256) void dec_gemm_kernel(const float* __restrict__ pooled,
                                                       const float* __restrict__ dec_w,
                                                       const float* __restrict__ dec_b,
                                                       u16* __restrict__ hp) {
    __shared__ __align__(16) u16 As[32 * 72];
    __shared__ __align__(16) u16 Bs[128 * 72];
    const int t = threadIdx.x;
    const int lane = t & 63;
    const int wid = t >> 6;
    const int wm = wid >> 1, wn = wid & 1;
    const int n0 = blockIdx.x * 128;
    const int g = lane >> 4, lr = lane & 15;

    const int ar = t >> 3;
    const int ak = (t & 7) * 8;
    const int bn4 = (t & 31) * 4;
    const int bk4 = (t >> 5) * 4;
    const int bswz = ((bn4 >> 2) & 3) << 3;
    const int bkp = (bk4 ^ bswz);

    f32x4 acc[4];
#pragma unroll
    for (int j = 0; j < 4; ++j) acc[j] = (f32x4){0.f, 0.f, 0.f, 0.f};

    f32x4 ra[2];
    f32x4 rb[2][4];
#pragma unroll
    for (int h = 0; h < 2; ++h)
        ra[h] = *reinterpret_cast<const f32x4*>(pooled + ar * 1024 + ak + h * 4);
#pragma unroll
    for (int q = 0; q < 2; ++q)
#pragma unroll
        for (int i = 0; i < 4; ++i)
            rb[q][i] = *reinterpret_cast<const f32x4*>(
                dec_w + (size_t)(bk4 + q * 32 + i) * 25088 + n0 + bn4);

    for (int k0 = 0; k0 < 1024; k0 += 64) {
        __syncthreads();
        {
            short8v o;
#pragma unroll
            for (int h = 0; h < 2; ++h) {
                o[h * 4 + 0] = f2bf(ra[h].x * (1.0f / 196.0f));
                o[h * 4 + 1] = f2bf(ra[h].y * (1.0f / 196.0f));
                o[h * 4 + 2] = f2bf(ra[h].z * (1.0f / 196.0f));
                o[h * 4 + 3] = f2bf(ra[h].w * (1.0f / 196.0f));
            }
            *reinterpret_cast<short8v*>(As + ar * 72 + ak) = o;
        }
#pragma unroll
        for (int q = 0; q < 2; ++q) {
#pragma unroll
            for (int j = 0; j < 4; ++j) {
                short4v o4;
                o4[0] = f2bf(rb[q][0][j]);
                o4[1] = f2bf(rb[q][1][j]);
                o4[2] = f2bf(rb[q][2][j]);
                o4[3] = f2bf(rb[q][3][j]);
                *reinterpret_cast<short4v*>(Bs + (bn4 + j) * 72 + bkp + q * 32) = o4;
            }
        }
        __syncthreads();
        if (k0 + 64 < 1024) {
#pragma unroll
            for (int h = 0; h < 2; ++h)
                ra[h] = *reinterpret_cast<const f32x4*>(
                    pooled + ar * 1024 + k0 + 64 + ak + h * 4);
#pragma unroll
            for (int q = 0; q < 2; ++q)
#pragma unroll
                for (int i = 0; i < 4; ++i)
                    rb[q][i] = *reinterpret_cast<const f32x4*>(
                        dec_w + (size_t)(k0 + 64 + bk4 + q * 32 + i) * 25088 + n0 + bn4);
        }
#pragma unroll
        for (int kk = 0; kk < 2; ++kk) {
            int row = wm * 16 + lr;
            short8v af = *reinterpret_cast<const short8v*>(As + row * 72 + kk * 32 + g * 8);
#pragma unroll
            for (int fn = 0; fn < 4; ++fn) {
                int col = wn * 64 + fn * 16 + lr;
                int ch = (kk * 32 + g * 8) ^ (((col >> 2) & 3) << 3);
                short8v bf8 = *reinterpret_cast<const short8v*>(Bs + col * 72 + ch);
                acc[fn] = __builtin_amdgcn_mfma_f32_16x16x32_bf16(af, bf8, acc[fn], 0, 0, 0);
            }
        }
    }
#pragma unroll
    for (int fn = 0; fn < 4; ++fn) {
#pragma unroll
        for (int r = 0; r < 4; ++r) {
            int row = wm * 16 + g * 4 + r;
            int col = n0 + wn * 64 + fn * 16 + lr;
            float v = acc[fn][r] + dec_b[col];
            int ic = col / 49, sp = col - ic * 49;
            int sy = sp / 7, sx = sp - sy * 7;
            hp[((size_t)row * 512 + ic) * 81 + (sy + 1) * 9 + sx + 1] = f2bf(v);
        }
    }
}

// ---------------------------------------------------------------------------
// softmax over K=512 with cosine scaling; writes attn (fp32, d_out) + bf16 copy
// ---------------------------------------------------------------------------
__global__ __launch_bounds__(256) void softmax_kernel(const float* __restrict__ dots,
                                                      const float* __restrict__ zn,
                                                      const float* __restrict__ pn,
                                                      float* __restrict__ attn,
                                                      u16* __restrict__ attn_bf) {
    int m = blockIdx.x;
    int t = threadIdx.x;
    float zm = zn[m];
    float d0 = dots[(size_t)m * 512 + t];
    float d1 = dots[(size_t)m * 512 + t + 256];
    float v0 = d0 / fmaxf(zm * pn[t], EPS_COS);
    float v1 = d1 / fmaxf(zm * pn[t + 256], EPS_COS);
    float mx = fmaxf(v0, v1);
#pragma unroll
    for (int off = 32; off > 0; off >>= 1) mx = fmaxf(mx, __shfl_down(mx, off));
    __shared__ float red[8];
    int wave = t >> 6, lane = t & 63;
    if (lane == 0) red[wave] = mx;
    __syncthreads();
    if (t == 0) red[4] = fmaxf(fmaxf(red[0], red[1]), fmaxf(red[2], red[3]));
    __syncthreads();
    mx = red[4];
    float e0 = expf(v0 - mx), e1 = expf(v1 - mx);
    float s = e0 + e1;
#pragma unroll
    for (int off = 32; off > 0; off >>= 1) s += __shfl_down(s, off);
    if (lane == 0) red[wave] = s;
    __syncthreads();
    if (t == 0) red[5] = 1.0f / (red[0] + red[1] + red[2] + red[3]);
    __syncthreads();
    float r = red[5];
    float a0 = e0 * r, a1 = e1 * r;
    attn[(size_t)m * 512 + t] = a0;
    attn[(size_t)m * 512 + t + 256] = a1;
    attn_bf[(size_t)m * 512 + t] = f2bf(a0);
    attn_bf[(size_t)m * 512 + t + 256] = f2bf(a1);
}

// ---------------------------------------------------------------------------
// im2col for convT1 parity classes: A[p][row=b*49+s][k=ic*4+tap] bf16
// ---------------------------------------------------------------------------
__global__ __launch_bounds__(256) void im2col_kernel(const u16* __restrict__ hp,
                                                     u16* __restrict__ A) {
    int idx = blockIdx.x * 256 + threadIdx.x;  // < 1,638,400
    int k8 = idx & 255;                        // 8 cols = 2 ic x 4 taps
    int pr = idx >> 8;
    int p = pr / 1600;
    int row = pr - p * 1600;
    short8v o = {0, 0, 0, 0, 0, 0, 0, 0};
    if (row < 1568) {
        int b = row / 49, s = row - b * 49;
        int sy = s / 7, sx = s - sy * 7;
        int r0 = sy + (p >> 1) + 1;
        int c0 = sx + (p & 1) + 1;
        int ic0 = k8 * 2;
        const u16* hb = hp + ((size_t)b * 512 + ic0) * 81;
#pragma unroll
        for (int j = 0; j < 2; ++j) {
            o[j * 4 + 0] = hb[r0 * 9 + c0];
            o[j * 4 + 1] = hb[r0 * 9 + c0 - 1];
            o[j * 4 + 2] = hb[(r0 - 1) * 9 + c0];
            o[j * 4 + 3] = hb[(r0 - 1) * 9 + c0 - 1];
            hb += 81;
        }
    }
    *reinterpret_cast<short8v*>(A + (size_t)idx * 8) = o;
}

// ---------------------------------------------------------------------------
// convT2 gather: out[o] = bias[oc] + sum_{<=4 taps} G[row][oc*16+ky*4+kx]
// ---------------------------------------------------------------------------
__global__ __launch_bounds__(256) void convt2_gather_kernel(const float* __restrict__ G,
                                                            const float* __restrict__ bias,
                                                            float* __restrict__ out) {
    int o = blockIdx.x * 256 + threadIdx.x;  // < 75264
    int ox = o % 28;
    int oy = (o / 28) % 28;
    int oc = (o / 784) % 3;
    int b = o / 2352;
    int by = (oy + 1) >> 1, bx = (ox + 1) >> 1;
    float acc = bias[oc];
#pragma unroll
    for (int ty = 0; ty < 2; ++ty) {
        int iy = by - ty;
        if ((unsigned)iy >= 14u) continue;
#pragma unroll
        for (int tx = 0; tx < 2; ++tx) {
            int ix = bx - tx;
            if ((unsigned)ix >= 14u) continue;
            int p = (iy & 1) * 2 + (ix & 1);
            int row = ((b * 4 + p) * 49) + (iy >> 1) * 7 + (ix >> 1);
            int ky = oy + 1 - 2 * iy, kx = ox + 1 - 2 * ix;
            acc += G[(size_t)row * 64 + oc * 16 + ky * 4 + kx];
        }
    }
    out[o] = acc;
}

// ---------------------------------------------------------------------------
extern "C" void kernel_launch(void* const* d_in, const int* in_sizes, int n_in,
                              void* d_out, int out_size, void* d_ws, size_t ws_size,
                              hipStream_t stream) {
    const float* z      = (const float*)d_in[0];  // [32,196,1024]
    const float* protos = (const float*)d_in[1];  // [512,1024]
    const float* gate_w = (const float*)d_in[2];  // [2048,1024]
    const float* gate_b = (const float*)d_in[3];  // [1024]
    const float* dec_w  = (const float*)d_in[4];  // [1024,25088]
    const float* dec_b  = (const float*)d_in[5];  // [25088]
    const float* ct1_w  = (const float*)d_in[6];  // [512,256,4,4]
    const float* ct1_b  = (const float*)d_in[7];  // [256]
    const float* ct2_w  = (const float*)d_in[8];  // [256,3,4,4]
    const float* ct2_b  = (const float*)d_in[9];  // [3]

    float* xout = (float*)d_out;   // x_recon 75264
    float* attn = xout + 75264;    // attn 3211264

    float* w = (float*)d_ws;
    float* pn        = w;                       // 512
    float* zn        = w + 512;                 // 6272
    float* pooled    = w + 6784;                // 32768 (atomic-accumulated token sums)
    u16*   wt1bf     = (u16*)(w + 51840);       // 2,097,152 u16 -> ends 1,100,416
    u16*   protos_bf = (u16*)(w + 1100416);     // 524288 u16
    u16*   protosT   = (u16*)(w + 1362560);     // 524288 u16
    u16*   gwT       = (u16*)(w + 1624704);     // 2,097,152 u16 -> ends 2,673,280
    u16*   attn_bf   = (u16*)(w + 2673280);     // 3,211,264 u16 -> ends 4,278,912
    u16*   Abig      = (u16*)(w + 4278912);     // [6272][2048] u16 -> ends 10,701,440
    u16*   A_cls     = (u16*)(w + 2673280);     // [4][1600][2048] u16 -> ends 9,226,880;
                                                //   overlay attn_bf+Abig (written at
                                                //   im2col, after all readers done)
    float* dots      = w + 10701440;            // 3,211,264 (dead after softmax)
    u16*   h2cb      = (u16*)(w + 11364992);    // bf16 [6272][256] -> ends 12,970,624
    u16*   hp        = (u16*)(w + 17123968);    // zero-padded h buffer -> ends 17,787,520
    float* G         = w + 17787520;            // [6272][64] fp32 -> ends 18,188,928
    u16*   wpad      = (u16*)(w + 18188928);    // [64][256] bf16 -> ends 18,197,120 (72.8MB)

    // merged prep: hp zero + ct1 wtrans + ct2 wpad + pooled zero
    prep_kernel<<<1256, 256, 0, stream>>>(hp, ct1_w, wt1bf, ct2_w, wpad, pooled);
    // fused norm + bf16 cvt (z -> Abig left half; protos -> protos_bf)
    norm_cvt_kernel<<<6272, 256, 0, stream>>>(z, Abig, 2048, zn);
    norm_cvt_kernel<<<512, 256, 0, stream>>>(protos, protos_bf, 1024, pn);
    transpose_cvt_kernel<<<dim3(16, 8), 256, 0, stream>>>(protos, protosT, 512, 1024);
    transpose_cvt_kernel<<<dim3(16, 32), 256, 0, stream>>>(gate_w, gwT, 2048, 1024);
    // dots = z @ protos^T (M=6272, N=512, K=1024), 64x128, 512 thr (8 waves)
    mfma_gemm_kernel<2, 2, 2, 4, 0, true><<<dim3(98, 4), 512, 0, stream>>>(
        Abig, 2048, 0, protos_bf, 1024, 0, 6272, 512, 1024,
        dots, nullptr, 0, nullptr, nullptr, nullptr, 0, nullptr);
    // softmax -> attn (fp32 out) + attn_bf
    softmax_kernel<<<6272, 256, 0, stream>>>(dots, zn, pn, attn, attn_bf);
    // z_hat = attn @ protos (M=6272, N=1024, K=512), 128x128, 512 thr
    mfma_gemm_kernel<4, 2, 2, 4, 1, true><<<dim3(49, 8), 512, 0, stream>>>(
        attn_bf, 512, 0, protosT, 512, 0, 6272, 1024, 512,
        nullptr, Abig + 1024, 2048, nullptr, nullptr, nullptr, 0, nullptr);
    // gate GEMM (K=2048) + sigmoid blend + fused pooling, 128x128, 512 thr
    mfma_gemm_kernel<4, 2, 2, 4, 2, true><<<dim3(49, 8), 512, 0, stream>>>(
        Abig, 2048, 0, gwT, 2048, 0, 6272, 1024, 2048,
        nullptr, nullptr, 0, gate_b, Abig, Abig + 1024, 2048, pooled);
    // decoder: single MFMA GEMM, dec_w fp32 read once, writes hp directly
    dec_gemm_kernel<<<196, 256, 0, stream>>>(pooled, dec_w, dec_b, hp);
    // convT1 as grouped MFMA GEMM, 32x64 tiles -> 800 blocks (256 thr)
    im2col_kernel<<<6400, 256, 0, stream>>>(hp, A_cls);
    mfma_gemm_kernel<1, 2, 2, 2, 3, false><<<dim3(50, 4, 4), 256, 0, stream>>>(
        A_cls, 2048, (size_t)1600 * 2048, wt1bf, 2048, (size_t)256 * 2048,
        1600, 256, 2048, nullptr, h2cb, 0, ct1_b, nullptr, nullptr, 0, nullptr);
    // convT2 as GEMM (M=6272, N=64, K=256), 32x64 tiles -> 196 blocks (256 thr)
    mfma_gemm_kernel<1, 2, 2, 2, 0, false><<<dim3(196, 1), 256, 0, stream>>>(
        h2cb, 256, 0, wpad, 256, 0, 6272, 64, 256,
        G, nullptr, 0, nullptr, nullptr, nullptr, 0, nullptr);
    convt2_gather_kernel<<<294, 256, 0, stream>>>(G, ct2_b, xout);
}